// Round 4
// baseline (443.763 us; speedup 1.0000x reference)
//
#include <hip/hip_runtime.h>

#define BB 32
#define CC 3
#define HH 128
#define WW 128
#define NN 1024
#define KK (CC*HH*WW)        // 49152
#define NROWS (CC*HH)        // 384
#define BH 8                 // batches per block
#define BSPLIT (BB/BH)       // 4
#define NF4 (NN/4)           // 256
#define STEP (1.0f/127.0f)

// ---- per-neuron normalization scale: scale[n] = sqrt(H*W/(Sx*Sy)) ----
__global__ void scale_kernel(const float* __restrict__ mu_x,
                             const float* __restrict__ mu_y,
                             const float* __restrict__ sigma_x,
                             const float* __restrict__ sigma_y,
                             float* __restrict__ scale) {
    int n = blockIdx.x * blockDim.x + threadIdx.x;
    if (n >= NN) return;
    float mux = mu_x[n], muy = mu_y[n];
    float isx = 1.0f / sigma_x[n], isy = 1.0f / sigma_y[n];
    float Sx = 0.f, Sy = 0.f;
    for (int i = 0; i < WW; ++i) {
        float dx = (i * STEP - mux) * isx;
        Sx += __expf(-dx * dx);
        float dy = (i * STEP - muy) * isy;
        Sy += __expf(-dy * dy);
    }
    scale[n] = sqrtf((float)(HH * WW) / (Sx * Sy));
}

// ---- gx[w][n] and gy[h][n]*scale[n] tables ----
__global__ void table_kernel(const float* __restrict__ mu_x,
                             const float* __restrict__ mu_y,
                             const float* __restrict__ sigma_x,
                             const float* __restrict__ sigma_y,
                             const float* __restrict__ scale,
                             float* __restrict__ gxt,
                             float* __restrict__ gyt) {
    int id = blockIdx.x * blockDim.x + threadIdx.x;   // 128*1024
    int n = id & (NN - 1);
    int i = id >> 10;
    float sx = sigma_x[n], sy = sigma_y[n];
    float dx = i * STEP - mu_x[n];
    float dy = i * STEP - mu_y[n];
    gxt[id] = __expf(-0.5f * dx * dx / (sx * sx));
    gyt[id] = __expf(-0.5f * dy * dy / (sy * sy)) * scale[n];
}

// ---- main (partials path): copy-free double-banked pipeline ----
// block = (row-group g, batch-slice b0); lane owns n = 4*tid..+3.
template <int RPBT>
__global__ __launch_bounds__(256, 5) void main_pipe(
    const float* __restrict__ weights,
    const float* __restrict__ x,
    const float* __restrict__ gxt,
    const float* __restrict__ gyt,
    float* __restrict__ part)
{
    constexpr int KS = NROWS / RPBT;          // 384 or 192
    __shared__ float tile[RPBT][WW][BH];
    const int tid = threadIdx.x;

    // XCD-aware swizzle: the 4 b-slice siblings of a row land consecutively
    // on the SAME XCD so weight re-reads hit that XCD's L2.
    const int wg  = blockIdx.x;               // 0 .. KS*BSPLIT-1
    const int xcd = wg & 7;
    const int p   = wg >> 3;
    const int g   = xcd * (KS / 8) + (p >> 2);
    const int bs  = p & 3;
    const int b0  = bs * BH;
    const int r0  = g * RPBT;

    // stage x[b0..b0+BH) rows r0..r0+RPBT into LDS transposed
    {
        const int b = tid & (BH - 1);
        const int c = tid >> 3;               // 0..31
#pragma unroll
        for (int rr = 0; rr < RPBT; ++rr) {
            const float4 v = *(const float4*)(
                x + (size_t)(b0 + b) * KK + (size_t)(r0 + rr) * WW + c * 4);
            tile[rr][c*4+0][b] = v.x;
            tile[rr][c*4+1][b] = v.y;
            tile[rr][c*4+2][b] = v.z;
            tile[rr][c*4+3][b] = v.w;
        }
    }
    __syncthreads();

    float acc[BH][4];
#pragma unroll
    for (int b = 0; b < BH; ++b)
        acc[b][0] = acc[b][1] = acc[b][2] = acc[b][3] = 0.f;

#pragma unroll
    for (int rr = 0; rr < RPBT; ++rr) {
        const int r = r0 + rr;
        const int h = r & (HH - 1);
        const float4 gys = ((const float4*)(gyt + (size_t)h * NN))[tid];
        const float4* wp  = (const float4*)(weights + (size_t)r * WW * NN) + tid;
        const float4* gxp = (const float4*)gxt + tid;

        float racc[BH][4];
#pragma unroll
        for (int b = 0; b < BH; ++b)
            racc[b][0] = racc[b][1] = racc[b][2] = racc[b][3] = 0.f;

        float4 wtb[2][2], gxb[2][2];

#define LOADP(BK, W)                                                    \
        {                                                               \
            wtb[BK][0] = wp[(size_t)(W) * NF4];                         \
            wtb[BK][1] = wp[(size_t)((W) + 1) * NF4];                   \
            gxb[BK][0] = gxp[(size_t)(W) * NF4];                        \
            gxb[BK][1] = gxp[(size_t)((W) + 1) * NF4];                  \
        }

#define COMP1(WT, GXV, WIDX)                                            \
        {                                                               \
            float4 t;                                                   \
            t.x = GXV.x * WT.x; t.y = GXV.y * WT.y;                     \
            t.z = GXV.z * WT.z; t.w = GXV.w * WT.w;                     \
            const float4* tr = (const float4*)&tile[rr][WIDX][0];       \
            float xs[BH];                                               \
            ((float4*)xs)[0] = tr[0]; ((float4*)xs)[1] = tr[1];         \
            _Pragma("unroll")                                           \
            for (int b = 0; b < BH; ++b) {                              \
                racc[b][0] = fmaf(xs[b], t.x, racc[b][0]);              \
                racc[b][1] = fmaf(xs[b], t.y, racc[b][1]);              \
                racc[b][2] = fmaf(xs[b], t.z, racc[b][2]);              \
                racc[b][3] = fmaf(xs[b], t.w, racc[b][3]);              \
            }                                                           \
        }

#define COMPP(BK, W)                                                    \
        {                                                               \
            COMP1(wtb[BK][0], gxb[BK][0], (W));                         \
            COMP1(wtb[BK][1], gxb[BK][1], (W) + 1);                     \
        }

        LOADP(0, 0);
        LOADP(1, 2);
        for (int w = 0; w < WW - 4; w += 4) {
            COMPP(0, w);          // bank0 loads issued one iteration ago
            LOADP(0, w + 4);
            COMPP(1, w + 2);      // bank1 loads still had 4 outstanding
            LOADP(1, w + 6);
        }
        COMPP(0, WW - 4);
        COMPP(1, WW - 2);

#undef COMPP
#undef COMP1
#undef LOADP

        // fold per-row gy*scale once
#pragma unroll
        for (int b = 0; b < BH; ++b) {
            acc[b][0] = fmaf(gys.x, racc[b][0], acc[b][0]);
            acc[b][1] = fmaf(gys.y, racc[b][1], acc[b][1]);
            acc[b][2] = fmaf(gys.z, racc[b][2], acc[b][2]);
            acc[b][3] = fmaf(gys.w, racc[b][3], acc[b][3]);
        }
    }

    // coalesced float4 stores into this block's private partial slice
    float* pp = part + ((size_t)g * BB + b0) * NN + tid * 4;
#pragma unroll
    for (int b = 0; b < BH; ++b)
        *(float4*)(pp + (size_t)b * NN) = *(float4*)&acc[b][0];
}

// ---- stage 2: out[cell] = sum_s part[s][cell], 2-way s-split + LDS ----
template <int KS>
__global__ __launch_bounds__(256) void reduce_kernel(const float* __restrict__ part,
                                                     float* __restrict__ out) {
    __shared__ float buf[256];
    const int t = threadIdx.x;
    const int half = t >> 7;                       // 0/1
    const int cell = blockIdx.x * 128 + (t & 127); // 256 blocks x 128 cells
    const int s0 = half * (KS / 2);
    float a = 0.f;
#pragma unroll 8
    for (int s = 0; s < KS / 2; ++s)
        a += part[(size_t)(s0 + s) * (BB * NN) + cell];
    buf[t] = a;
    __syncthreads();
    if (t < 128) out[cell] = buf[t] + buf[t + 128];
}

// ---- fallback (atomic) path: proven R3 kernel, MODE 1 = tables, 2 = inline ----
template <int MODE>
__global__ __launch_bounds__(256) void main_fallback(
    const float* __restrict__ weights,
    const float* __restrict__ x,
    const float* __restrict__ gxt,
    const float* __restrict__ gyt,
    const float* __restrict__ mu_x, const float* __restrict__ mu_y,
    const float* __restrict__ sigma_x, const float* __restrict__ sigma_y,
    float* __restrict__ dst)
{
    __shared__ float tile[2][WW][BH];
    const int tid = threadIdx.x;
    const int g   = blockIdx.x;           // 0..191
    const int b0  = blockIdx.y * BH;
    const int r0  = g * 2;

    {
        const int b = tid & (BH - 1);
        const int c = tid >> 3;
        const float* xp = x + (size_t)(b0 + b) * KK + (size_t)r0 * WW + c * 8;
        const float4 v0 = ((const float4*)xp)[0];
        const float4 v1 = ((const float4*)xp)[1];
        const int row = (c * 8) >> 7;
        const int w   = (c * 8) & (WW - 1);
        tile[row][w+0][b] = v0.x; tile[row][w+1][b] = v0.y;
        tile[row][w+2][b] = v0.z; tile[row][w+3][b] = v0.w;
        tile[row][w+4][b] = v1.x; tile[row][w+5][b] = v1.y;
        tile[row][w+6][b] = v1.z; tile[row][w+7][b] = v1.w;
    }

    float4 mux4, ax4, ay4, muy4, sc4;
    if constexpr (MODE == 2) {
        mux4 = ((const float4*)mu_x)[tid];
        muy4 = ((const float4*)mu_y)[tid];
        float4 sx4 = ((const float4*)sigma_x)[tid];
        float4 sy4 = ((const float4*)sigma_y)[tid];
        ax4.x=-0.5f/(sx4.x*sx4.x); ax4.y=-0.5f/(sx4.y*sx4.y);
        ax4.z=-0.5f/(sx4.z*sx4.z); ax4.w=-0.5f/(sx4.w*sx4.w);
        ay4.x=-0.5f/(sy4.x*sy4.x); ay4.y=-0.5f/(sy4.y*sy4.y);
        ay4.z=-0.5f/(sy4.z*sy4.z); ay4.w=-0.5f/(sy4.w*sy4.w);
        float Sx[4]={0,0,0,0}, Sy[4]={0,0,0,0};
        for (int i = 0; i < WW; ++i) {
            float pp = i * STEP, d;
            d=pp-mux4.x; Sx[0]+=__expf(2.f*ax4.x*d*d);
            d=pp-mux4.y; Sx[1]+=__expf(2.f*ax4.y*d*d);
            d=pp-mux4.z; Sx[2]+=__expf(2.f*ax4.z*d*d);
            d=pp-mux4.w; Sx[3]+=__expf(2.f*ax4.w*d*d);
            d=pp-muy4.x; Sy[0]+=__expf(2.f*ay4.x*d*d);
            d=pp-muy4.y; Sy[1]+=__expf(2.f*ay4.y*d*d);
            d=pp-muy4.z; Sy[2]+=__expf(2.f*ay4.z*d*d);
            d=pp-muy4.w; Sy[3]+=__expf(2.f*ay4.w*d*d);
        }
        sc4.x = sqrtf((float)(HH*WW)/(Sx[0]*Sy[0]));
        sc4.y = sqrtf((float)(HH*WW)/(Sx[1]*Sy[1]));
        sc4.z = sqrtf((float)(HH*WW)/(Sx[2]*Sy[2]));
        sc4.w = sqrtf((float)(HH*WW)/(Sx[3]*Sy[3]));
    }
    __syncthreads();

    float acc[BH][4];
#pragma unroll
    for (int b = 0; b < BH; ++b)
        acc[b][0] = acc[b][1] = acc[b][2] = acc[b][3] = 0.f;

#pragma unroll
    for (int rr = 0; rr < 2; ++rr) {
        const int r = r0 + rr;
        const int h = r & (HH - 1);
        float4 gys;
        if constexpr (MODE == 2) {
            float hp = h * STEP, d;
            d=hp-muy4.x; gys.x = __expf(ay4.x*d*d) * sc4.x;
            d=hp-muy4.y; gys.y = __expf(ay4.y*d*d) * sc4.y;
            d=hp-muy4.z; gys.z = __expf(ay4.z*d*d) * sc4.z;
            d=hp-muy4.w; gys.w = __expf(ay4.w*d*d) * sc4.w;
        } else {
            gys = ((const float4*)(gyt + (size_t)h * NN))[tid];
        }
        const float4* wp  = (const float4*)(weights + (size_t)r * WW * NN) + tid;
        const float4* gxp = (const float4*)gxt + tid;
        float racc[BH][4];
#pragma unroll
        for (int b = 0; b < BH; ++b)
            racc[b][0] = racc[b][1] = racc[b][2] = racc[b][3] = 0.f;
        auto GX = [&](int w) -> float4 {
            if constexpr (MODE == 2) {
                float pp = w * STEP, d;
                float4 gg;
                d=pp-mux4.x; gg.x = __expf(ax4.x*d*d);
                d=pp-mux4.y; gg.y = __expf(ax4.y*d*d);
                d=pp-mux4.z; gg.z = __expf(ax4.z*d*d);
                d=pp-mux4.w; gg.w = __expf(ax4.w*d*d);
                return gg;
            } else {
                return gxp[(size_t)w * NF4];
            }
        };
#define COMPUTE(WIDX, WT, GXV)                                          \
        {                                                               \
            float4 t;                                                   \
            t.x = GXV.x * WT.x; t.y = GXV.y * WT.y;                     \
            t.z = GXV.z * WT.z; t.w = GXV.w * WT.w;                     \
            const float4* tr = (const float4*)&tile[rr][WIDX][0];       \
            float xs[BH];                                               \
            ((float4*)xs)[0] = tr[0]; ((float4*)xs)[1] = tr[1];         \
            _Pragma("unroll")                                           \
            for (int b = 0; b < BH; ++b) {                              \
                racc[b][0] = fmaf(xs[b], t.x, racc[b][0]);              \
                racc[b][1] = fmaf(xs[b], t.y, racc[b][1]);              \
                racc[b][2] = fmaf(xs[b], t.z, racc[b][2]);              \
                racc[b][3] = fmaf(xs[b], t.w, racc[b][3]);              \
            }                                                           \
        }
        float4 wtA = wp[0];
        float4 gxA = GX(0);
        float4 wtB = wp[NF4];
        float4 gxB = GX(1);
        for (int w = 0; w < WW; w += 2) {
            const int wn = (w + 2 < WW) ? (w + 2) : (WW - 2);
            float4 wtA2 = wp[(size_t)wn * NF4];
            float4 gxA2 = GX(wn);
            float4 wtB2 = wp[(size_t)(wn + 1) * NF4];
            float4 gxB2 = GX(wn + 1);
            COMPUTE(w,     wtA, gxA);
            COMPUTE(w + 1, wtB, gxB);
            wtA = wtA2; gxA = gxA2; wtB = wtB2; gxB = gxB2;
        }
#undef COMPUTE
#pragma unroll
        for (int b = 0; b < BH; ++b) {
            acc[b][0] = fmaf(gys.x, racc[b][0], acc[b][0]);
            acc[b][1] = fmaf(gys.y, racc[b][1], acc[b][1]);
            acc[b][2] = fmaf(gys.z, racc[b][2], acc[b][2]);
            acc[b][3] = fmaf(gys.w, racc[b][3], acc[b][3]);
        }
    }

    float* op = dst + (size_t)b0 * NN + tid * 4;
#pragma unroll
    for (int b = 0; b < BH; ++b) {
        atomicAdd(op + (size_t)b * NN + 0, acc[b][0]);
        atomicAdd(op + (size_t)b * NN + 1, acc[b][1]);
        atomicAdd(op + (size_t)b * NN + 2, acc[b][2]);
        atomicAdd(op + (size_t)b * NN + 3, acc[b][3]);
    }
}

extern "C" void kernel_launch(void* const* d_in, const int* in_sizes, int n_in,
                              void* d_out, int out_size, void* d_ws, size_t ws_size,
                              hipStream_t stream) {
    const float* x       = (const float*)d_in[0];
    const float* mu_x    = (const float*)d_in[1];
    const float* mu_y    = (const float*)d_in[2];
    const float* sigma_x = (const float*)d_in[3];
    const float* sigma_y = (const float*)d_in[4];
    const float* weights = (const float*)d_in[5];
    float* out = (float*)d_out;

    float* scale = (float*)d_ws;                          // 4 KB
    float* gxt   = (float*)((char*)d_ws + 4096);          // 512 KB
    float* gyt   = gxt + (size_t)HH * NN;                 // 512 KB
    float* part  = gyt + (size_t)HH * NN;
    const size_t need_tbl = 4096 + 2 * sizeof(float) * (size_t)HH * NN;
    const size_t need_p1  = need_tbl + sizeof(float) * (size_t)NROWS     * BB * NN; // 50.3 MB
    const size_t need_p2  = need_tbl + sizeof(float) * (size_t)(NROWS/2) * BB * NN; // 25.2 MB

    if (ws_size >= need_p2) {
        scale_kernel<<<(NN + 255) / 256, 256, 0, stream>>>(mu_x, mu_y, sigma_x, sigma_y, scale);
        table_kernel<<<(HH * NN) / 256, 256, 0, stream>>>(mu_x, mu_y, sigma_x, sigma_y,
                                                          scale, gxt, gyt);
        if (ws_size >= need_p1) {
            main_pipe<1><<<NROWS * BSPLIT, 256, 0, stream>>>(weights, x, gxt, gyt, part);
            reduce_kernel<NROWS><<<BB * NN / 128, 256, 0, stream>>>(part, out);
        } else {
            main_pipe<2><<<(NROWS/2) * BSPLIT, 256, 0, stream>>>(weights, x, gxt, gyt, part);
            reduce_kernel<NROWS/2><<<BB * NN / 128, 256, 0, stream>>>(part, out);
        }
    } else if (ws_size >= need_tbl) {
        hipMemsetAsync(d_out, 0, (size_t)out_size * sizeof(float), stream);
        scale_kernel<<<(NN + 255) / 256, 256, 0, stream>>>(mu_x, mu_y, sigma_x, sigma_y, scale);
        table_kernel<<<(HH * NN) / 256, 256, 0, stream>>>(mu_x, mu_y, sigma_x, sigma_y,
                                                          scale, gxt, gyt);
        dim3 grid(NROWS/2, BSPLIT);
        main_fallback<1><<<grid, 256, 0, stream>>>(weights, x, gxt, gyt,
                                                   mu_x, mu_y, sigma_x, sigma_y, out);
    } else {
        hipMemsetAsync(d_out, 0, (size_t)out_size * sizeof(float), stream);
        dim3 grid(NROWS/2, BSPLIT);
        main_fallback<2><<<grid, 256, 0, stream>>>(weights, x, nullptr, nullptr,
                                                   mu_x, mu_y, sigma_x, sigma_y, out);
    }
}

// Round 5
// 95.225 us; speedup vs baseline: 4.6601x; 4.6601x over previous
//
#include <hip/hip_runtime.h>
#include <stdint.h>

#define BB 32
#define CC 3
#define HH 128
#define WW 128
#define NN 1024
#define KK (CC*HH*WW)        // 49152
#define NROWS (CC*HH)        // 384
#define RPB 2                // rows per block
#define KS (NROWS/RPB)       // 192 row-groups
#define BH 8                 // batches per block
#define BSPLIT (BB/BH)       // 4
#define NF4 (NN/4)           // 256
#define WCH 8                // w-columns per LDS chunk
#define NCH ((RPB*WW)/WCH)   // 32 chunks per block
#define STEP (1.0f/127.0f)

// ---- per-neuron normalization scale: scale[n] = sqrt(H*W/(Sx*Sy)) ----
__global__ void scale_kernel(const float* __restrict__ mu_x,
                             const float* __restrict__ mu_y,
                             const float* __restrict__ sigma_x,
                             const float* __restrict__ sigma_y,
                             float* __restrict__ scale) {
    int n = blockIdx.x * blockDim.x + threadIdx.x;
    if (n >= NN) return;
    float mux = mu_x[n], muy = mu_y[n];
    float isx = 1.0f / sigma_x[n], isy = 1.0f / sigma_y[n];
    float Sx = 0.f, Sy = 0.f;
    for (int i = 0; i < WW; ++i) {
        float dx = (i * STEP - mux) * isx;
        Sx += __expf(-dx * dx);
        float dy = (i * STEP - muy) * isy;
        Sy += __expf(-dy * dy);
    }
    scale[n] = sqrtf((float)(HH * WW) / (Sx * Sy));
}

// ---- gx[w][n] (fallback only) and gy[h][n]*scale[n] tables ----
__global__ void table_kernel(const float* __restrict__ mu_x,
                             const float* __restrict__ mu_y,
                             const float* __restrict__ sigma_x,
                             const float* __restrict__ sigma_y,
                             const float* __restrict__ scale,
                             float* __restrict__ gxt,
                             float* __restrict__ gyt) {
    int id = blockIdx.x * blockDim.x + threadIdx.x;   // 128*1024
    int n = id & (NN - 1);
    int i = id >> 10;
    float sx = sigma_x[n], sy = sigma_y[n];
    float dx = i * STEP - mu_x[n];
    float dy = i * STEP - mu_y[n];
    gxt[id] = __expf(-0.5f * dx * dx / (sx * sx));
    gyt[id] = __expf(-0.5f * dy * dy / (sy * sy)) * scale[n];
}

// ---- main: LDS-staged weights (global_load_lds dbuf) + gx recurrence ----
// block = (row-group g, batch-slice b0); lane owns n = 4*tid..+3.
__global__ __launch_bounds__(256) void main_pipe(
    const float* __restrict__ weights,
    const float* __restrict__ x,
    const float* __restrict__ gyt,
    const float* __restrict__ mu_x,
    const float* __restrict__ sigma_x,
    float* __restrict__ part)
{
    __shared__ float wbuf[2][WCH * NN];    // 2 x 32 KB weight chunks
    __shared__ float xtile[RPB][WW][BH];   // 8 KB
    const int tid = threadIdx.x;

    // XCD swizzle: 4 b-slice siblings of a row-group -> same XCD, adjacent.
    const int d    = blockIdx.x;           // 0..KS*BSPLIT-1 (768)
    const int xcd  = d & 7;
    const int slot = d >> 3;               // 0..95
    const int g    = xcd * (KS / 8) + (slot >> 2);   // 0..191
    const int b0   = (slot & 3) * BH;
    const int r0   = g * RPB;

    // stage x[b0..b0+8) rows r0..r0+1 into LDS transposed
    {
        const int b = tid & (BH - 1);
        const int c = tid >> 3;            // 0..31
#pragma unroll
        for (int rr = 0; rr < RPB; ++rr) {
            const float4 v = *(const float4*)(
                x + (size_t)(b0 + b) * KK + (size_t)(r0 + rr) * WW + c * 4);
            xtile[rr][c*4+0][b] = v.x;
            xtile[rr][c*4+1][b] = v.y;
            xtile[rr][c*4+2][b] = v.z;
            xtile[rr][c*4+3][b] = v.w;
        }
    }

    // per-lane gx-recurrence constants (4 neurons/lane)
    const float4 mux = ((const float4*)mu_x)[tid];
    const float4 sx  = ((const float4*)sigma_x)[tid];
    float4 ax, axs, Bf;
    ax.x = -0.5f/(sx.x*sx.x); ax.y = -0.5f/(sx.y*sx.y);
    ax.z = -0.5f/(sx.z*sx.z); ax.w = -0.5f/(sx.w*sx.w);
    axs.x = ax.x*STEP; axs.y = ax.y*STEP; axs.z = ax.z*STEP; axs.w = ax.w*STEP;
    Bf.x = __expf(2.f*axs.x*STEP); Bf.y = __expf(2.f*axs.y*STEP);
    Bf.z = __expf(2.f*axs.z*STEP); Bf.w = __expf(2.f*axs.w*STEP);

    // async global->LDS staging of one 32 KB weight chunk (wave-split)
    auto stage = [&](int c) {
        const int rr = c >> 4;
        const int w0 = (c & 15) * WCH;
        const float* gsrc = weights + ((size_t)(r0 + rr) * WW + w0) * NN;
        float* lb = wbuf[c & 1];
        const int q = tid >> 6;            // wave id 0..3
        const int lane = tid & 63;
#pragma unroll
        for (int i = 0; i < 8; ++i) {
            const int off = q * 2048 + i * 256;   // floats
            __builtin_amdgcn_global_load_lds(
                (const __attribute__((address_space(1))) unsigned int*)(gsrc + off + lane * 4),
                (__attribute__((address_space(3))) unsigned int*)(lb + off),
                16, 0, 0);
        }
    };

    stage(0);
    __syncthreads();

    float4 acc[BH];
#pragma unroll
    for (int b = 0; b < BH; ++b) acc[b] = make_float4(0.f, 0.f, 0.f, 0.f);

    float4 g4, r4, gyrow;
    for (int c = 0; c < NCH; ++c) {
        if (c + 1 < NCH) stage(c + 1);     // prefetch flies during compute

        const int rr = c >> 4;
        const int w0 = (c & 15) * WCH;
        if ((c & 15) == 0) {               // new row: load gy[h]*scale
            const int h = (r0 + rr) & (HH - 1);
            gyrow = ((const float4*)(gyt + (size_t)h * NN))[tid];
        }
        // resync recurrence at w0 (fresh exps -> error span <= 8 steps)
        {
            float dd;
            dd = w0*STEP - mux.x; g4.x = __expf(ax.x*dd*dd)*gyrow.x; r4.x = __expf(axs.x*(2.f*dd+STEP));
            dd = w0*STEP - mux.y; g4.y = __expf(ax.y*dd*dd)*gyrow.y; r4.y = __expf(axs.y*(2.f*dd+STEP));
            dd = w0*STEP - mux.z; g4.z = __expf(ax.z*dd*dd)*gyrow.z; r4.z = __expf(axs.z*(2.f*dd+STEP));
            dd = w0*STEP - mux.w; g4.w = __expf(ax.w*dd*dd)*gyrow.w; r4.w = __expf(axs.w*(2.f*dd+STEP));
        }

        const float* wb = wbuf[c & 1];
#pragma unroll
        for (int i = 0; i < WCH; ++i) {
            const float4 wt = *(const float4*)(wb + i * NN + (tid << 2));  // ds_read_b128, conflict-free
            const float4* tr = (const float4*)&xtile[rr][w0 + i][0];       // uniform -> broadcast
            float xs[BH];
            ((float4*)xs)[0] = tr[0]; ((float4*)xs)[1] = tr[1];
            float4 t;
            t.x = g4.x * wt.x; t.y = g4.y * wt.y;
            t.z = g4.z * wt.z; t.w = g4.w * wt.w;
#pragma unroll
            for (int b = 0; b < BH; ++b) {
                acc[b].x = fmaf(xs[b], t.x, acc[b].x);
                acc[b].y = fmaf(xs[b], t.y, acc[b].y);
                acc[b].z = fmaf(xs[b], t.z, acc[b].z);
                acc[b].w = fmaf(xs[b], t.w, acc[b].w);
            }
            g4.x *= r4.x; g4.y *= r4.y; g4.z *= r4.z; g4.w *= r4.w;
            r4.x *= Bf.x; r4.y *= Bf.y; r4.z *= Bf.z; r4.w *= Bf.w;
        }
        __syncthreads();                   // makes chunk c+1 ready, protects dbuf
    }

    // coalesced float4 stores into this block's private partial slice
    float* pp = part + ((size_t)g * BB + b0) * NN + (tid << 2);
#pragma unroll
    for (int b = 0; b < BH; ++b)
        *(float4*)(pp + (size_t)b * NN) = acc[b];
}

// ---- stage 2: out[cell] = sum_s part[s][cell], 2-way s-split + LDS ----
template <int KSS>
__global__ __launch_bounds__(256) void reduce_kernel(const float* __restrict__ part,
                                                     float* __restrict__ out) {
    __shared__ float buf[256];
    const int t = threadIdx.x;
    const int half = t >> 7;
    const int cell = blockIdx.x * 128 + (t & 127);
    const int s0 = half * (KSS / 2);
    float a = 0.f;
#pragma unroll 8
    for (int s = 0; s < KSS / 2; ++s)
        a += part[(size_t)(s0 + s) * (BB * NN) + cell];
    buf[t] = a;
    __syncthreads();
    if (t < 128) out[cell] = buf[t] + buf[t + 128];
}

// ---- fallback (atomic) path — proven R3 kernel ----
template <int MODE>
__global__ __launch_bounds__(256) void main_fallback(
    const float* __restrict__ weights,
    const float* __restrict__ x,
    const float* __restrict__ gxt,
    const float* __restrict__ gyt,
    const float* __restrict__ mu_x, const float* __restrict__ mu_y,
    const float* __restrict__ sigma_x, const float* __restrict__ sigma_y,
    float* __restrict__ dst)
{
    __shared__ float tile[2][WW][BH];
    const int tid = threadIdx.x;
    const int g   = blockIdx.x;
    const int b0  = blockIdx.y * BH;
    const int r0  = g * 2;

    {
        const int b = tid & (BH - 1);
        const int c = tid >> 3;
        const float* xp = x + (size_t)(b0 + b) * KK + (size_t)r0 * WW + c * 8;
        const float4 v0 = ((const float4*)xp)[0];
        const float4 v1 = ((const float4*)xp)[1];
        const int row = (c * 8) >> 7;
        const int w   = (c * 8) & (WW - 1);
        tile[row][w+0][b] = v0.x; tile[row][w+1][b] = v0.y;
        tile[row][w+2][b] = v0.z; tile[row][w+3][b] = v0.w;
        tile[row][w+4][b] = v1.x; tile[row][w+5][b] = v1.y;
        tile[row][w+6][b] = v1.z; tile[row][w+7][b] = v1.w;
    }

    float4 mux4, ax4, ay4, muy4, sc4;
    if constexpr (MODE == 2) {
        mux4 = ((const float4*)mu_x)[tid];
        muy4 = ((const float4*)mu_y)[tid];
        float4 sx4 = ((const float4*)sigma_x)[tid];
        float4 sy4 = ((const float4*)sigma_y)[tid];
        ax4.x=-0.5f/(sx4.x*sx4.x); ax4.y=-0.5f/(sx4.y*sx4.y);
        ax4.z=-0.5f/(sx4.z*sx4.z); ax4.w=-0.5f/(sx4.w*sx4.w);
        ay4.x=-0.5f/(sy4.x*sy4.x); ay4.y=-0.5f/(sy4.y*sy4.y);
        ay4.z=-0.5f/(sy4.z*sy4.z); ay4.w=-0.5f/(sy4.w*sy4.w);
        float Sx[4]={0,0,0,0}, Sy[4]={0,0,0,0};
        for (int i = 0; i < WW; ++i) {
            float pp = i * STEP, dd;
            dd=pp-mux4.x; Sx[0]+=__expf(2.f*ax4.x*dd*dd);
            dd=pp-mux4.y; Sx[1]+=__expf(2.f*ax4.y*dd*dd);
            dd=pp-mux4.z; Sx[2]+=__expf(2.f*ax4.z*dd*dd);
            dd=pp-mux4.w; Sx[3]+=__expf(2.f*ax4.w*dd*dd);
            dd=pp-muy4.x; Sy[0]+=__expf(2.f*ay4.x*dd*dd);
            dd=pp-muy4.y; Sy[1]+=__expf(2.f*ay4.y*dd*dd);
            dd=pp-muy4.z; Sy[2]+=__expf(2.f*ay4.z*dd*dd);
            dd=pp-muy4.w; Sy[3]+=__expf(2.f*ay4.w*dd*dd);
        }
        sc4.x = sqrtf((float)(HH*WW)/(Sx[0]*Sy[0]));
        sc4.y = sqrtf((float)(HH*WW)/(Sx[1]*Sy[1]));
        sc4.z = sqrtf((float)(HH*WW)/(Sx[2]*Sy[2]));
        sc4.w = sqrtf((float)(HH*WW)/(Sx[3]*Sy[3]));
    }
    __syncthreads();

    float acc[BH][4];
#pragma unroll
    for (int b = 0; b < BH; ++b)
        acc[b][0] = acc[b][1] = acc[b][2] = acc[b][3] = 0.f;

#pragma unroll
    for (int rr = 0; rr < 2; ++rr) {
        const int r = r0 + rr;
        const int h = r & (HH - 1);
        float4 gys;
        if constexpr (MODE == 2) {
            float hp = h * STEP, dd;
            dd=hp-muy4.x; gys.x = __expf(ay4.x*dd*dd) * sc4.x;
            dd=hp-muy4.y; gys.y = __expf(ay4.y*dd*dd) * sc4.y;
            dd=hp-muy4.z; gys.z = __expf(ay4.z*dd*dd) * sc4.z;
            dd=hp-muy4.w; gys.w = __expf(ay4.w*dd*dd) * sc4.w;
        } else {
            gys = ((const float4*)(gyt + (size_t)h * NN))[tid];
        }
        const float4* wp  = (const float4*)(weights + (size_t)r * WW * NN) + tid;
        const float4* gxp = (const float4*)gxt + tid;
        float racc[BH][4];
#pragma unroll
        for (int b = 0; b < BH; ++b)
            racc[b][0] = racc[b][1] = racc[b][2] = racc[b][3] = 0.f;
        auto GX = [&](int w) -> float4 {
            if constexpr (MODE == 2) {
                float pp = w * STEP, dd;
                float4 gg;
                dd=pp-mux4.x; gg.x = __expf(ax4.x*dd*dd);
                dd=pp-mux4.y; gg.y = __expf(ax4.y*dd*dd);
                dd=pp-mux4.z; gg.z = __expf(ax4.z*dd*dd);
                dd=pp-mux4.w; gg.w = __expf(ax4.w*dd*dd);
                return gg;
            } else {
                return gxp[(size_t)w * NF4];
            }
        };
#define COMPUTE(WIDX, WT, GXV)                                          \
        {                                                               \
            float4 t;                                                   \
            t.x = GXV.x * WT.x; t.y = GXV.y * WT.y;                     \
            t.z = GXV.z * WT.z; t.w = GXV.w * WT.w;                     \
            const float4* tr = (const float4*)&tile[rr][WIDX][0];       \
            float xs[BH];                                               \
            ((float4*)xs)[0] = tr[0]; ((float4*)xs)[1] = tr[1];         \
            _Pragma("unroll")                                           \
            for (int b = 0; b < BH; ++b) {                              \
                racc[b][0] = fmaf(xs[b], t.x, racc[b][0]);              \
                racc[b][1] = fmaf(xs[b], t.y, racc[b][1]);              \
                racc[b][2] = fmaf(xs[b], t.z, racc[b][2]);              \
                racc[b][3] = fmaf(xs[b], t.w, racc[b][3]);              \
            }                                                           \
        }
        float4 wtA = wp[0];
        float4 gxA = GX(0);
        float4 wtB = wp[NF4];
        float4 gxB = GX(1);
        for (int w = 0; w < WW; w += 2) {
            const int wn = (w + 2 < WW) ? (w + 2) : (WW - 2);
            float4 wtA2 = wp[(size_t)wn * NF4];
            float4 gxA2 = GX(wn);
            float4 wtB2 = wp[(size_t)(wn + 1) * NF4];
            float4 gxB2 = GX(wn + 1);
            COMPUTE(w,     wtA, gxA);
            COMPUTE(w + 1, wtB, gxB);
            wtA = wtA2; gxA = gxA2; wtB = wtB2; gxB = gxB2;
        }
#undef COMPUTE
#pragma unroll
        for (int b = 0; b < BH; ++b) {
            acc[b][0] = fmaf(gys.x, racc[b][0], acc[b][0]);
            acc[b][1] = fmaf(gys.y, racc[b][1], acc[b][1]);
            acc[b][2] = fmaf(gys.z, racc[b][2], acc[b][2]);
            acc[b][3] = fmaf(gys.w, racc[b][3], acc[b][3]);
        }
    }

    float* op = dst + (size_t)b0 * NN + tid * 4;
#pragma unroll
    for (int b = 0; b < BH; ++b) {
        atomicAdd(op + (size_t)b * NN + 0, acc[b][0]);
        atomicAdd(op + (size_t)b * NN + 1, acc[b][1]);
        atomicAdd(op + (size_t)b * NN + 2, acc[b][2]);
        atomicAdd(op + (size_t)b * NN + 3, acc[b][3]);
    }
}

extern "C" void kernel_launch(void* const* d_in, const int* in_sizes, int n_in,
                              void* d_out, int out_size, void* d_ws, size_t ws_size,
                              hipStream_t stream) {
    const float* x       = (const float*)d_in[0];
    const float* mu_x    = (const float*)d_in[1];
    const float* mu_y    = (const float*)d_in[2];
    const float* sigma_x = (const float*)d_in[3];
    const float* sigma_y = (const float*)d_in[4];
    const float* weights = (const float*)d_in[5];
    float* out = (float*)d_out;

    float* scale = (float*)d_ws;                          // 4 KB
    float* gxt   = (float*)((char*)d_ws + 4096);          // 512 KB
    float* gyt   = gxt + (size_t)HH * NN;                 // 512 KB
    float* part  = gyt + (size_t)HH * NN;                 // 25.2 MB
    const size_t need_tbl  = 4096 + 2 * sizeof(float) * (size_t)HH * NN;
    const size_t need_part = need_tbl + sizeof(float) * (size_t)KS * BB * NN;

    if (ws_size >= need_part) {
        scale_kernel<<<(NN + 255) / 256, 256, 0, stream>>>(mu_x, mu_y, sigma_x, sigma_y, scale);
        table_kernel<<<(HH * NN) / 256, 256, 0, stream>>>(mu_x, mu_y, sigma_x, sigma_y,
                                                          scale, gxt, gyt);
        main_pipe<<<KS * BSPLIT, 256, 0, stream>>>(weights, x, gyt, mu_x, sigma_x, part);
        reduce_kernel<KS><<<BB * NN / 128, 256, 0, stream>>>(part, out);
    } else if (ws_size >= need_tbl) {
        hipMemsetAsync(d_out, 0, (size_t)out_size * sizeof(float), stream);
        scale_kernel<<<(NN + 255) / 256, 256, 0, stream>>>(mu_x, mu_y, sigma_x, sigma_y, scale);
        table_kernel<<<(HH * NN) / 256, 256, 0, stream>>>(mu_x, mu_y, sigma_x, sigma_y,
                                                          scale, gxt, gyt);
        dim3 grid(KS, BSPLIT);
        main_fallback<1><<<grid, 256, 0, stream>>>(weights, x, gxt, gyt,
                                                   mu_x, mu_y, sigma_x, sigma_y, out);
    } else {
        hipMemsetAsync(d_out, 0, (size_t)out_size * sizeof(float), stream);
        dim3 grid(KS, BSPLIT);
        main_fallback<2><<<grid, 256, 0, stream>>>(weights, x, nullptr, nullptr,
                                                   mu_x, mu_y, sigma_x, sigma_y, out);
    }
}

// Round 6
// 83.002 us; speedup vs baseline: 5.3464x; 1.1473x over previous
//
#include <hip/hip_runtime.h>
#include <stdint.h>

#define BB 32
#define CC 3
#define HH 128
#define WW 128
#define NN 1024
#define KK (CC*HH*WW)        // 49152
#define NROWS (CC*HH)        // 384
#define KSR NROWS            // 384 row-groups (1 row each)
#define BH 16                // batches per block
#define BSPLIT (BB/BH)       // 2
#define NF4 (NN/4)           // 256
#define WCH 4                // w-columns per LDS chunk (16 KB)
#define NCH (WW/WCH)         // 32 chunks per block
#define STEP (1.0f/127.0f)

// ---- per-neuron normalization scale: scale[n] = sqrt(H*W/(Sx*Sy)) ----
__global__ void scale_kernel(const float* __restrict__ mu_x,
                             const float* __restrict__ mu_y,
                             const float* __restrict__ sigma_x,
                             const float* __restrict__ sigma_y,
                             float* __restrict__ scale) {
    int n = blockIdx.x * blockDim.x + threadIdx.x;
    if (n >= NN) return;
    float mux = mu_x[n], muy = mu_y[n];
    float isx = 1.0f / sigma_x[n], isy = 1.0f / sigma_y[n];
    float Sx = 0.f, Sy = 0.f;
    for (int i = 0; i < WW; ++i) {
        float dx = (i * STEP - mux) * isx;
        Sx += __expf(-dx * dx);
        float dy = (i * STEP - muy) * isy;
        Sy += __expf(-dy * dy);
    }
    scale[n] = sqrtf((float)(HH * WW) / (Sx * Sy));
}

// ---- gx[w][n] (fallback only) and gy[h][n]*scale[n] tables ----
__global__ void table_kernel(const float* __restrict__ mu_x,
                             const float* __restrict__ mu_y,
                             const float* __restrict__ sigma_x,
                             const float* __restrict__ sigma_y,
                             const float* __restrict__ scale,
                             float* __restrict__ gxt,
                             float* __restrict__ gyt) {
    int id = blockIdx.x * blockDim.x + threadIdx.x;   // 128*1024
    int n = id & (NN - 1);
    int i = id >> 10;
    float sx = sigma_x[n], sy = sigma_y[n];
    float dx = i * STEP - mu_x[n];
    float dy = i * STEP - mu_y[n];
    gxt[id] = __expf(-0.5f * dx * dx / (sx * sx));
    gyt[id] = __expf(-0.5f * dy * dy / (sy * sy)) * scale[n];
}

// ---- main: one row per block, 16 batches, 4-col LDS weight chunks ----
// block = (row g, batch-half b0); lane owns n = 4*tid..+3.
__global__ __launch_bounds__(256) void main_pipe(
    const float* __restrict__ weights,
    const float* __restrict__ x,
    const float* __restrict__ gyt,
    const float* __restrict__ mu_x,
    const float* __restrict__ sigma_x,
    float* __restrict__ part)
{
    __shared__ float wbuf[2][WCH * NN];    // 2 x 16 KB
    __shared__ float xtile[WW][BH];        // 8 KB
    const int tid = threadIdx.x;

    // XCD swizzle: the 2 batch-half siblings of a row -> same XCD, adjacent.
    const int d    = blockIdx.x;           // 0..KSR*BSPLIT-1 (768)
    const int xcd  = d & 7;
    const int slot = d >> 3;               // 0..95
    const int g    = xcd * (KSR / 8) + (slot >> 1);   // 0..383
    const int b0   = (slot & 1) * BH;
    const int r    = g;
    const int h    = r & (HH - 1);

    // stage x[b0..b0+16) row r into LDS transposed
    {
        const int b = tid & (BH - 1);
        const int c = tid >> 4;            // 0..15, 8 w each
        const float* xp = x + (size_t)(b0 + b) * KK + (size_t)r * WW + c * 8;
        const float4 v0 = ((const float4*)xp)[0];
        const float4 v1 = ((const float4*)xp)[1];
        const int w = c * 8;
        xtile[w+0][b] = v0.x; xtile[w+1][b] = v0.y;
        xtile[w+2][b] = v0.z; xtile[w+3][b] = v0.w;
        xtile[w+4][b] = v1.x; xtile[w+5][b] = v1.y;
        xtile[w+6][b] = v1.z; xtile[w+7][b] = v1.w;
    }

    // per-lane gx-recurrence constants (4 neurons/lane)
    const float4 mux = ((const float4*)mu_x)[tid];
    const float4 sx  = ((const float4*)sigma_x)[tid];
    float4 ax, axs, Bf;
    ax.x = -0.5f/(sx.x*sx.x); ax.y = -0.5f/(sx.y*sx.y);
    ax.z = -0.5f/(sx.z*sx.z); ax.w = -0.5f/(sx.w*sx.w);
    axs.x = ax.x*STEP; axs.y = ax.y*STEP; axs.z = ax.z*STEP; axs.w = ax.w*STEP;
    Bf.x = __expf(2.f*axs.x*STEP); Bf.y = __expf(2.f*axs.y*STEP);
    Bf.z = __expf(2.f*axs.z*STEP); Bf.w = __expf(2.f*axs.w*STEP);

    const float4 gyrow = ((const float4*)(gyt + (size_t)h * NN))[tid];

    // async global->LDS staging of one 16 KB weight chunk (wave-split)
    auto stage = [&](int c) {
        const int w0 = c * WCH;
        const float* gsrc = weights + ((size_t)r * WW + w0) * NN;
        float* lb = wbuf[c & 1];
        const int q = tid >> 6;            // wave id 0..3
        const int lane = tid & 63;
#pragma unroll
        for (int i = 0; i < 4; ++i) {
            const int off = q * 1024 + i * 256;   // floats
            __builtin_amdgcn_global_load_lds(
                (const __attribute__((address_space(1))) unsigned int*)(gsrc + off + lane * 4),
                (__attribute__((address_space(3))) unsigned int*)(lb + off),
                16, 0, 0);
        }
    };

    stage(0);
    __syncthreads();

    float4 acc[BH];
#pragma unroll
    for (int b = 0; b < BH; ++b) acc[b] = make_float4(0.f, 0.f, 0.f, 0.f);

    for (int c = 0; c < NCH; ++c) {
        if (c + 1 < NCH) stage(c + 1);     // prefetch flies during compute

        const int w0 = c * WCH;
        // resync recurrence at w0 (fresh exps -> error span <= 4 steps),
        // gy[h]*scale folded into the seed
        float4 g4, r4;
        {
            float dd;
            dd = w0*STEP - mux.x; g4.x = __expf(ax.x*dd*dd)*gyrow.x; r4.x = __expf(axs.x*(2.f*dd+STEP));
            dd = w0*STEP - mux.y; g4.y = __expf(ax.y*dd*dd)*gyrow.y; r4.y = __expf(axs.y*(2.f*dd+STEP));
            dd = w0*STEP - mux.z; g4.z = __expf(ax.z*dd*dd)*gyrow.z; r4.z = __expf(axs.z*(2.f*dd+STEP));
            dd = w0*STEP - mux.w; g4.w = __expf(ax.w*dd*dd)*gyrow.w; r4.w = __expf(axs.w*(2.f*dd+STEP));
        }

        const float* wb = wbuf[c & 1];
#pragma unroll
        for (int i = 0; i < WCH; ++i) {
            const float4 wt = *(const float4*)(wb + i * NN + (tid << 2));  // ds_read_b128
            const float4* tr = (const float4*)&xtile[w0 + i][0];           // uniform -> broadcast
            float4 t;
            t.x = g4.x * wt.x; t.y = g4.y * wt.y;
            t.z = g4.z * wt.z; t.w = g4.w * wt.w;
#pragma unroll
            for (int q = 0; q < 4; ++q) {
                const float4 xv = tr[q];               // one xv live at a time
                acc[4*q+0].x = fmaf(xv.x, t.x, acc[4*q+0].x);
                acc[4*q+0].y = fmaf(xv.x, t.y, acc[4*q+0].y);
                acc[4*q+0].z = fmaf(xv.x, t.z, acc[4*q+0].z);
                acc[4*q+0].w = fmaf(xv.x, t.w, acc[4*q+0].w);
                acc[4*q+1].x = fmaf(xv.y, t.x, acc[4*q+1].x);
                acc[4*q+1].y = fmaf(xv.y, t.y, acc[4*q+1].y);
                acc[4*q+1].z = fmaf(xv.y, t.z, acc[4*q+1].z);
                acc[4*q+1].w = fmaf(xv.y, t.w, acc[4*q+1].w);
                acc[4*q+2].x = fmaf(xv.z, t.x, acc[4*q+2].x);
                acc[4*q+2].y = fmaf(xv.z, t.y, acc[4*q+2].y);
                acc[4*q+2].z = fmaf(xv.z, t.z, acc[4*q+2].z);
                acc[4*q+2].w = fmaf(xv.z, t.w, acc[4*q+2].w);
                acc[4*q+3].x = fmaf(xv.w, t.x, acc[4*q+3].x);
                acc[4*q+3].y = fmaf(xv.w, t.y, acc[4*q+3].y);
                acc[4*q+3].z = fmaf(xv.w, t.z, acc[4*q+3].z);
                acc[4*q+3].w = fmaf(xv.w, t.w, acc[4*q+3].w);
            }
            g4.x *= r4.x; g4.y *= r4.y; g4.z *= r4.z; g4.w *= r4.w;
            r4.x *= Bf.x; r4.y *= Bf.y; r4.z *= Bf.z; r4.w *= Bf.w;
        }
        __syncthreads();                   // chunk c+1 ready, protects dbuf
    }

    // coalesced float4 stores into this block's private partial slice
    float* pp = part + ((size_t)g * BB + b0) * NN + (tid << 2);
#pragma unroll
    for (int b = 0; b < BH; ++b)
        *(float4*)(pp + (size_t)b * NN) = acc[b];
}

// ---- stage 2: out[cell] = sum_s part[s][cell], 2-way s-split + LDS ----
template <int KSS>
__global__ __launch_bounds__(256) void reduce_kernel(const float* __restrict__ part,
                                                     float* __restrict__ out) {
    __shared__ float buf[256];
    const int t = threadIdx.x;
    const int half = t >> 7;
    const int cell = blockIdx.x * 128 + (t & 127);
    const int s0 = half * (KSS / 2);
    float a = 0.f;
#pragma unroll 8
    for (int s = 0; s < KSS / 2; ++s)
        a += part[(size_t)(s0 + s) * (BB * NN) + cell];
    buf[t] = a;
    __syncthreads();
    if (t < 128) out[cell] = buf[t] + buf[t + 128];
}

// ---- fallback (atomic) path — proven R3 kernel ----
template <int MODE>
__global__ __launch_bounds__(256) void main_fallback(
    const float* __restrict__ weights,
    const float* __restrict__ x,
    const float* __restrict__ gxt,
    const float* __restrict__ gyt,
    const float* __restrict__ mu_x, const float* __restrict__ mu_y,
    const float* __restrict__ sigma_x, const float* __restrict__ sigma_y,
    float* __restrict__ dst)
{
    __shared__ float tile[2][WW][8];
    const int tid = threadIdx.x;
    const int g   = blockIdx.x;
    const int b0  = blockIdx.y * 8;
    const int r0  = g * 2;

    {
        const int b = tid & 7;
        const int c = tid >> 3;
        const float* xp = x + (size_t)(b0 + b) * KK + (size_t)r0 * WW + c * 8;
        const float4 v0 = ((const float4*)xp)[0];
        const float4 v1 = ((const float4*)xp)[1];
        const int row = (c * 8) >> 7;
        const int w   = (c * 8) & (WW - 1);
        tile[row][w+0][b] = v0.x; tile[row][w+1][b] = v0.y;
        tile[row][w+2][b] = v0.z; tile[row][w+3][b] = v0.w;
        tile[row][w+4][b] = v1.x; tile[row][w+5][b] = v1.y;
        tile[row][w+6][b] = v1.z; tile[row][w+7][b] = v1.w;
    }

    float4 mux4, ax4, ay4, muy4, sc4;
    if constexpr (MODE == 2) {
        mux4 = ((const float4*)mu_x)[tid];
        muy4 = ((const float4*)mu_y)[tid];
        float4 sx4 = ((const float4*)sigma_x)[tid];
        float4 sy4 = ((const float4*)sigma_y)[tid];
        ax4.x=-0.5f/(sx4.x*sx4.x); ax4.y=-0.5f/(sx4.y*sx4.y);
        ax4.z=-0.5f/(sx4.z*sx4.z); ax4.w=-0.5f/(sx4.w*sx4.w);
        ay4.x=-0.5f/(sy4.x*sy4.x); ay4.y=-0.5f/(sy4.y*sy4.y);
        ay4.z=-0.5f/(sy4.z*sy4.z); ay4.w=-0.5f/(sy4.w*sy4.w);
        float Sx[4]={0,0,0,0}, Sy[4]={0,0,0,0};
        for (int i = 0; i < WW; ++i) {
            float pp = i * STEP, dd;
            dd=pp-mux4.x; Sx[0]+=__expf(2.f*ax4.x*dd*dd);
            dd=pp-mux4.y; Sx[1]+=__expf(2.f*ax4.y*dd*dd);
            dd=pp-mux4.z; Sx[2]+=__expf(2.f*ax4.z*dd*dd);
            dd=pp-mux4.w; Sx[3]+=__expf(2.f*ax4.w*dd*dd);
            dd=pp-muy4.x; Sy[0]+=__expf(2.f*ay4.x*dd*dd);
            dd=pp-muy4.y; Sy[1]+=__expf(2.f*ay4.y*dd*dd);
            dd=pp-muy4.z; Sy[2]+=__expf(2.f*ay4.z*dd*dd);
            dd=pp-muy4.w; Sy[3]+=__expf(2.f*ay4.w*dd*dd);
        }
        sc4.x = sqrtf((float)(HH*WW)/(Sx[0]*Sy[0]));
        sc4.y = sqrtf((float)(HH*WW)/(Sx[1]*Sy[1]));
        sc4.z = sqrtf((float)(HH*WW)/(Sx[2]*Sy[2]));
        sc4.w = sqrtf((float)(HH*WW)/(Sx[3]*Sy[3]));
    }
    __syncthreads();

    float acc[8][4];
#pragma unroll
    for (int b = 0; b < 8; ++b)
        acc[b][0] = acc[b][1] = acc[b][2] = acc[b][3] = 0.f;

#pragma unroll
    for (int rr = 0; rr < 2; ++rr) {
        const int rrow = r0 + rr;
        const int hh = rrow & (HH - 1);
        float4 gys;
        if constexpr (MODE == 2) {
            float hp = hh * STEP, dd;
            dd=hp-muy4.x; gys.x = __expf(ay4.x*dd*dd) * sc4.x;
            dd=hp-muy4.y; gys.y = __expf(ay4.y*dd*dd) * sc4.y;
            dd=hp-muy4.z; gys.z = __expf(ay4.z*dd*dd) * sc4.z;
            dd=hp-muy4.w; gys.w = __expf(ay4.w*dd*dd) * sc4.w;
        } else {
            gys = ((const float4*)(gyt + (size_t)hh * NN))[tid];
        }
        const float4* wp  = (const float4*)(weights + (size_t)rrow * WW * NN) + tid;
        const float4* gxp = (const float4*)gxt + tid;
        float racc[8][4];
#pragma unroll
        for (int b = 0; b < 8; ++b)
            racc[b][0] = racc[b][1] = racc[b][2] = racc[b][3] = 0.f;
        auto GX = [&](int w) -> float4 {
            if constexpr (MODE == 2) {
                float pp = w * STEP, dd;
                float4 gg;
                dd=pp-mux4.x; gg.x = __expf(ax4.x*dd*dd);
                dd=pp-mux4.y; gg.y = __expf(ax4.y*dd*dd);
                dd=pp-mux4.z; gg.z = __expf(ax4.z*dd*dd);
                dd=pp-mux4.w; gg.w = __expf(ax4.w*dd*dd);
                return gg;
            } else {
                return gxp[(size_t)w * NF4];
            }
        };
#define COMPUTE(WIDX, WT, GXV)                                          \
        {                                                               \
            float4 t;                                                   \
            t.x = GXV.x * WT.x; t.y = GXV.y * WT.y;                     \
            t.z = GXV.z * WT.z; t.w = GXV.w * WT.w;                     \
            const float4* tr = (const float4*)&tile[rr][WIDX][0];       \
            float xs[8];                                                \
            ((float4*)xs)[0] = tr[0]; ((float4*)xs)[1] = tr[1];         \
            _Pragma("unroll")                                           \
            for (int b = 0; b < 8; ++b) {                               \
                racc[b][0] = fmaf(xs[b], t.x, racc[b][0]);              \
                racc[b][1] = fmaf(xs[b], t.y, racc[b][1]);              \
                racc[b][2] = fmaf(xs[b], t.z, racc[b][2]);              \
                racc[b][3] = fmaf(xs[b], t.w, racc[b][3]);              \
            }                                                           \
        }
        float4 wtA = wp[0];
        float4 gxA = GX(0);
        float4 wtB = wp[NF4];
        float4 gxB = GX(1);
        for (int w = 0; w < WW; w += 2) {
            const int wn = (w + 2 < WW) ? (w + 2) : (WW - 2);
            float4 wtA2 = wp[(size_t)wn * NF4];
            float4 gxA2 = GX(wn);
            float4 wtB2 = wp[(size_t)(wn + 1) * NF4];
            float4 gxB2 = GX(wn + 1);
            COMPUTE(w,     wtA, gxA);
            COMPUTE(w + 1, wtB, gxB);
            wtA = wtA2; gxA = gxA2; wtB = wtB2; gxB = gxB2;
        }
#undef COMPUTE
#pragma unroll
        for (int b = 0; b < 8; ++b) {
            acc[b][0] = fmaf(gys.x, racc[b][0], acc[b][0]);
            acc[b][1] = fmaf(gys.y, racc[b][1], acc[b][1]);
            acc[b][2] = fmaf(gys.z, racc[b][2], acc[b][2]);
            acc[b][3] = fmaf(gys.w, racc[b][3], acc[b][3]);
        }
    }

    float* op = dst + (size_t)b0 * NN + tid * 4;
#pragma unroll
    for (int b = 0; b < 8; ++b) {
        atomicAdd(op + (size_t)b * NN + 0, acc[b][0]);
        atomicAdd(op + (size_t)b * NN + 1, acc[b][1]);
        atomicAdd(op + (size_t)b * NN + 2, acc[b][2]);
        atomicAdd(op + (size_t)b * NN + 3, acc[b][3]);
    }
}

extern "C" void kernel_launch(void* const* d_in, const int* in_sizes, int n_in,
                              void* d_out, int out_size, void* d_ws, size_t ws_size,
                              hipStream_t stream) {
    const float* x       = (const float*)d_in[0];
    const float* mu_x    = (const float*)d_in[1];
    const float* mu_y    = (const float*)d_in[2];
    const float* sigma_x = (const float*)d_in[3];
    const float* sigma_y = (const float*)d_in[4];
    const float* weights = (const float*)d_in[5];
    float* out = (float*)d_out;

    float* scale = (float*)d_ws;                          // 4 KB
    float* gxt   = (float*)((char*)d_ws + 4096);          // 512 KB
    float* gyt   = gxt + (size_t)HH * NN;                 // 512 KB
    float* part  = gyt + (size_t)HH * NN;                 // 50.3 MB
    const size_t need_tbl  = 4096 + 2 * sizeof(float) * (size_t)HH * NN;
    const size_t need_part = need_tbl + sizeof(float) * (size_t)KSR * BB * NN;

    if (ws_size >= need_part) {
        scale_kernel<<<(NN + 255) / 256, 256, 0, stream>>>(mu_x, mu_y, sigma_x, sigma_y, scale);
        table_kernel<<<(HH * NN) / 256, 256, 0, stream>>>(mu_x, mu_y, sigma_x, sigma_y,
                                                          scale, gxt, gyt);
        main_pipe<<<KSR * BSPLIT, 256, 0, stream>>>(weights, x, gyt, mu_x, sigma_x, part);
        reduce_kernel<KSR><<<BB * NN / 128, 256, 0, stream>>>(part, out);
    } else if (ws_size >= need_tbl) {
        hipMemsetAsync(d_out, 0, (size_t)out_size * sizeof(float), stream);
        scale_kernel<<<(NN + 255) / 256, 256, 0, stream>>>(mu_x, mu_y, sigma_x, sigma_y, scale);
        table_kernel<<<(HH * NN) / 256, 256, 0, stream>>>(mu_x, mu_y, sigma_x, sigma_y,
                                                          scale, gxt, gyt);
        dim3 grid(NROWS / 2, 4);
        main_fallback<1><<<grid, 256, 0, stream>>>(weights, x, gxt, gyt,
                                                   mu_x, mu_y, sigma_x, sigma_y, out);
    } else {
        hipMemsetAsync(d_out, 0, (size_t)out_size * sizeof(float), stream);
        dim3 grid(NROWS / 2, 4);
        main_fallback<2><<<grid, 256, 0, stream>>>(weights, x, nullptr, nullptr,
                                                   mu_x, mu_y, sigma_x, sigma_y, out);
    }
}

// Round 7
// 78.907 us; speedup vs baseline: 5.6239x; 1.0519x over previous
//
#include <hip/hip_runtime.h>
#include <stdint.h>

#define BB 32
#define CC 3
#define HH 128
#define WW 128
#define NN 1024
#define KK (CC*HH*WW)        // 49152
#define NROWS (CC*HH)        // 384
#define KSR NROWS            // 384 split-K groups (1 row each)
#define BH 16                // batches per block
#define BSPLIT (BB/BH)       // 2
#define NF4 (NN/4)           // 256
#define WCH 4                // w-columns per chunk
#define NCH (WW/WCH)         // 32 chunks per row
#define SG 8                 // s-groups in reduce stage 1
#define STEP (1.0f/127.0f)

// ---- per-neuron normalization scale: scale[n] = sqrt(H*W/(Sx*Sy)) ----
__global__ void scale_kernel(const float* __restrict__ mu_x,
                             const float* __restrict__ mu_y,
                             const float* __restrict__ sigma_x,
                             const float* __restrict__ sigma_y,
                             float* __restrict__ scale) {
    int n = blockIdx.x * blockDim.x + threadIdx.x;
    if (n >= NN) return;
    float mux = mu_x[n], muy = mu_y[n];
    float isx = 1.0f / sigma_x[n], isy = 1.0f / sigma_y[n];
    float Sx = 0.f, Sy = 0.f;
    for (int i = 0; i < WW; ++i) {
        float dx = (i * STEP - mux) * isx;
        Sx += __expf(-dx * dx);
        float dy = (i * STEP - muy) * isy;
        Sy += __expf(-dy * dy);
    }
    scale[n] = sqrtf((float)(HH * WW) / (Sx * Sy));
}

// ---- gx[w][n] (fallback only) and gy[h][n]*scale[n] tables ----
__global__ void table_kernel(const float* __restrict__ mu_x,
                             const float* __restrict__ mu_y,
                             const float* __restrict__ sigma_x,
                             const float* __restrict__ sigma_y,
                             const float* __restrict__ scale,
                             float* __restrict__ gxt,
                             float* __restrict__ gyt) {
    int id = blockIdx.x * blockDim.x + threadIdx.x;   // 128*1024
    int n = id & (NN - 1);
    int i = id >> 10;
    float sx = sigma_x[n], sy = sigma_y[n];
    float dx = i * STEP - mu_x[n];
    float dy = i * STEP - mu_y[n];
    gxt[id] = __expf(-0.5f * dx * dx / (sx * sx));
    gyt[id] = __expf(-0.5f * dy * dy / (sy * sy)) * scale[n];
}

// ---- main v3: wave-private pipelines, counted vmcnt, no k-loop barriers ----
// block = (row g, batch-half b0); wave owns a 256-n slice; lane owns n=4*tid..+3
__global__ __launch_bounds__(256) void main_pipe(
    const float* __restrict__ weights,
    const float* __restrict__ x,
    const float* __restrict__ gyt,
    const float* __restrict__ mu_x,
    const float* __restrict__ sigma_x,
    float* __restrict__ part)
{
    __shared__ float wbuf[4][2][WCH][256];   // per-wave double-buffer, 32 KB
    __shared__ float xtile[WW][BH];          // 8 KB
    const int tid  = threadIdx.x;
    const int wv   = tid >> 6;               // wave 0..3
    const int lane = tid & 63;

    // XCD swizzle: the 2 batch-half siblings of a row -> same XCD, adjacent.
    const int d    = blockIdx.x;             // 0..767
    const int xcd  = d & 7;
    const int slot = d >> 3;                 // 0..95
    const int g    = xcd * (KSR / 8) + (slot >> 1);   // 0..383
    const int b0   = (slot & 1) * BH;
    const int r    = g;
    const int h    = r & (HH - 1);

    // stage x[b0..b0+16) row r into LDS transposed
    {
        const int b = tid & (BH - 1);
        const int c = tid >> 4;              // 0..15, 8 w each
        const float* xp = x + (size_t)(b0 + b) * KK + (size_t)r * WW + c * 8;
        const float4 v0 = ((const float4*)xp)[0];
        const float4 v1 = ((const float4*)xp)[1];
        const int w = c * 8;
        xtile[w+0][b] = v0.x; xtile[w+1][b] = v0.y;
        xtile[w+2][b] = v0.z; xtile[w+3][b] = v0.w;
        xtile[w+4][b] = v1.x; xtile[w+5][b] = v1.y;
        xtile[w+6][b] = v1.z; xtile[w+7][b] = v1.w;
    }

    // per-lane gx-recurrence constants (4 neurons/lane)
    const float4 mux = ((const float4*)mu_x)[tid];
    const float4 sx  = ((const float4*)sigma_x)[tid];
    float4 ax, axs, Bf;
    ax.x = -0.5f/(sx.x*sx.x); ax.y = -0.5f/(sx.y*sx.y);
    ax.z = -0.5f/(sx.z*sx.z); ax.w = -0.5f/(sx.w*sx.w);
    axs.x = ax.x*STEP; axs.y = ax.y*STEP; axs.z = ax.z*STEP; axs.w = ax.w*STEP;
    Bf.x = __expf(2.f*axs.x*STEP); Bf.y = __expf(2.f*axs.y*STEP);
    Bf.z = __expf(2.f*axs.z*STEP); Bf.w = __expf(2.f*axs.w*STEP);

    const float4 gyrow = ((const float4*)(gyt + (size_t)h * NN))[tid];  // gy*scale

    // per-wave async staging of one 4 KB chunk slice (4 x global_load_lds_x4)
    const float* wrow = weights + (size_t)r * WW * NN + wv * 256 + lane * 4;
    auto stage = [&](int c) {
        const float* gsrc = wrow + (size_t)(c * WCH) * NN;
        float* lb = &wbuf[wv][c & 1][0][0];
#pragma unroll
        for (int i = 0; i < WCH; ++i) {
            __builtin_amdgcn_global_load_lds(
                (const __attribute__((address_space(1))) unsigned int*)(gsrc + (size_t)i * NN),
                (__attribute__((address_space(3))) unsigned int*)(lb + i * 256),
                16, 0, 0);
        }
    };

    __syncthreads();                         // xtile ready (only barrier)
    stage(0);

    float4 acc[BH];
#pragma unroll
    for (int b = 0; b < BH; ++b) acc[b] = make_float4(0.f, 0.f, 0.f, 0.f);

    float4 g4, r4;
    for (int c = 0; c < NCH; ++c) {
        if (c + 1 < NCH) stage(c + 1);       // keep 4 loads in flight

        if ((c & 3) == 0) {                  // resync recurrence (span 16)
            const float w0s = (float)(c * WCH) * STEP;
            float dd;
            dd = w0s - mux.x; g4.x = __expf(ax.x*dd*dd)*gyrow.x; r4.x = __expf(axs.x*(2.f*dd+STEP));
            dd = w0s - mux.y; g4.y = __expf(ax.y*dd*dd)*gyrow.y; r4.y = __expf(axs.y*(2.f*dd+STEP));
            dd = w0s - mux.z; g4.z = __expf(ax.z*dd*dd)*gyrow.z; r4.z = __expf(axs.z*(2.f*dd+STEP));
            dd = w0s - mux.w; g4.w = __expf(ax.w*dd*dd)*gyrow.w; r4.w = __expf(axs.w*(2.f*dd+STEP));
        }

        // wait for chunk c's 4 loads only (c+1's 4 stay outstanding)
        if (c + 1 < NCH) {
            asm volatile("s_waitcnt vmcnt(4)" ::: "memory");
        } else {
            asm volatile("s_waitcnt vmcnt(0)" ::: "memory");
        }
        __builtin_amdgcn_sched_barrier(0);

        const float* wb = &wbuf[wv][c & 1][0][0];
        const int w0 = c * WCH;
#pragma unroll
        for (int i = 0; i < WCH; ++i) {
            const float4 wt = *(const float4*)(wb + i * 256 + (lane << 2));
            const float4* tr = (const float4*)&xtile[w0 + i][0];   // uniform -> broadcast
            float4 t;
            t.x = g4.x * wt.x; t.y = g4.y * wt.y;
            t.z = g4.z * wt.z; t.w = g4.w * wt.w;
#pragma unroll
            for (int q = 0; q < 4; ++q) {
                const float4 xv = tr[q];
                acc[4*q+0].x = fmaf(xv.x, t.x, acc[4*q+0].x);
                acc[4*q+0].y = fmaf(xv.x, t.y, acc[4*q+0].y);
                acc[4*q+0].z = fmaf(xv.x, t.z, acc[4*q+0].z);
                acc[4*q+0].w = fmaf(xv.x, t.w, acc[4*q+0].w);
                acc[4*q+1].x = fmaf(xv.y, t.x, acc[4*q+1].x);
                acc[4*q+1].y = fmaf(xv.y, t.y, acc[4*q+1].y);
                acc[4*q+1].z = fmaf(xv.y, t.z, acc[4*q+1].z);
                acc[4*q+1].w = fmaf(xv.y, t.w, acc[4*q+1].w);
                acc[4*q+2].x = fmaf(xv.z, t.x, acc[4*q+2].x);
                acc[4*q+2].y = fmaf(xv.z, t.y, acc[4*q+2].y);
                acc[4*q+2].z = fmaf(xv.z, t.z, acc[4*q+2].z);
                acc[4*q+2].w = fmaf(xv.z, t.w, acc[4*q+2].w);
                acc[4*q+3].x = fmaf(xv.w, t.x, acc[4*q+3].x);
                acc[4*q+3].y = fmaf(xv.w, t.y, acc[4*q+3].y);
                acc[4*q+3].z = fmaf(xv.w, t.z, acc[4*q+3].z);
                acc[4*q+3].w = fmaf(xv.w, t.w, acc[4*q+3].w);
            }
            g4.x *= r4.x; g4.y *= r4.y; g4.z *= r4.z; g4.w *= r4.w;
            r4.x *= Bf.x; r4.y *= Bf.y; r4.z *= Bf.z; r4.w *= Bf.w;
        }
    }

    // coalesced float4 stores into this block's private partial slice
    float* pp = part + ((size_t)g * BB + b0) * NN + (tid << 2);
#pragma unroll
    for (int b = 0; b < BH; ++b)
        *(float4*)(pp + (size_t)b * NN) = acc[b];
}

// ---- reduce stage 1: part2[sg][cq] = sum over 48 s of part[s][cq] (float4) ----
__global__ __launch_bounds__(256) void reduce1_kernel(const float* __restrict__ part,
                                                      float* __restrict__ part2) {
    const int sg = blockIdx.x >> 5;                       // 0..7
    const int cq = (blockIdx.x & 31) * 256 + threadIdx.x; // 0..8191 cell-quads
    const int s0 = sg * (KSR / SG);
    float4 a = make_float4(0.f, 0.f, 0.f, 0.f);
#pragma unroll 4
    for (int s = 0; s < KSR / SG; ++s) {
        const float4 v = *(const float4*)(part + (size_t)(s0 + s) * (BB * NN) + cq * 4);
        a.x += v.x; a.y += v.y; a.z += v.z; a.w += v.w;
    }
    *(float4*)(part2 + ((size_t)sg * (BB * NN) + cq * 4)) = a;
}

// ---- reduce stage 2: out[cq] = sum over 8 s-groups ----
__global__ __launch_bounds__(256) void reduce2_kernel(const float* __restrict__ part2,
                                                      float* __restrict__ out) {
    const int cq = blockIdx.x * 256 + threadIdx.x;        // 0..8191
    float4 a = make_float4(0.f, 0.f, 0.f, 0.f);
#pragma unroll
    for (int sgi = 0; sgi < SG; ++sgi) {
        const float4 v = *(const float4*)(part2 + (size_t)sgi * (BB * NN) + cq * 4);
        a.x += v.x; a.y += v.y; a.z += v.z; a.w += v.w;
    }
    *(float4*)(out + cq * 4) = a;
}

// ---- fallback (atomic) path — proven R3 kernel ----
template <int MODE>
__global__ __launch_bounds__(256) void main_fallback(
    const float* __restrict__ weights,
    const float* __restrict__ x,
    const float* __restrict__ gxt,
    const float* __restrict__ gyt,
    const float* __restrict__ mu_x, const float* __restrict__ mu_y,
    const float* __restrict__ sigma_x, const float* __restrict__ sigma_y,
    float* __restrict__ dst)
{
    __shared__ float tile[2][WW][8];
    const int tid = threadIdx.x;
    const int g   = blockIdx.x;
    const int b0  = blockIdx.y * 8;
    const int r0  = g * 2;

    {
        const int b = tid & 7;
        const int c = tid >> 3;
        const float* xp = x + (size_t)(b0 + b) * KK + (size_t)r0 * WW + c * 8;
        const float4 v0 = ((const float4*)xp)[0];
        const float4 v1 = ((const float4*)xp)[1];
        const int row = (c * 8) >> 7;
        const int w   = (c * 8) & (WW - 1);
        tile[row][w+0][b] = v0.x; tile[row][w+1][b] = v0.y;
        tile[row][w+2][b] = v0.z; tile[row][w+3][b] = v0.w;
        tile[row][w+4][b] = v1.x; tile[row][w+5][b] = v1.y;
        tile[row][w+6][b] = v1.z; tile[row][w+7][b] = v1.w;
    }

    float4 mux4, ax4, ay4, muy4, sc4;
    if constexpr (MODE == 2) {
        mux4 = ((const float4*)mu_x)[tid];
        muy4 = ((const float4*)mu_y)[tid];
        float4 sx4 = ((const float4*)sigma_x)[tid];
        float4 sy4 = ((const float4*)sigma_y)[tid];
        ax4.x=-0.5f/(sx4.x*sx4.x); ax4.y=-0.5f/(sx4.y*sx4.y);
        ax4.z=-0.5f/(sx4.z*sx4.z); ax4.w=-0.5f/(sx4.w*sx4.w);
        ay4.x=-0.5f/(sy4.x*sy4.x); ay4.y=-0.5f/(sy4.y*sy4.y);
        ay4.z=-0.5f/(sy4.z*sy4.z); ay4.w=-0.5f/(sy4.w*sy4.w);
        float Sx[4]={0,0,0,0}, Sy[4]={0,0,0,0};
        for (int i = 0; i < WW; ++i) {
            float pp = i * STEP, dd;
            dd=pp-mux4.x; Sx[0]+=__expf(2.f*ax4.x*dd*dd);
            dd=pp-mux4.y; Sx[1]+=__expf(2.f*ax4.y*dd*dd);
            dd=pp-mux4.z; Sx[2]+=__expf(2.f*ax4.z*dd*dd);
            dd=pp-mux4.w; Sx[3]+=__expf(2.f*ax4.w*dd*dd);
            dd=pp-muy4.x; Sy[0]+=__expf(2.f*ay4.x*dd*dd);
            dd=pp-muy4.y; Sy[1]+=__expf(2.f*ay4.y*dd*dd);
            dd=pp-muy4.z; Sy[2]+=__expf(2.f*ay4.z*dd*dd);
            dd=pp-muy4.w; Sy[3]+=__expf(2.f*ay4.w*dd*dd);
        }
        sc4.x = sqrtf((float)(HH*WW)/(Sx[0]*Sy[0]));
        sc4.y = sqrtf((float)(HH*WW)/(Sx[1]*Sy[1]));
        sc4.z = sqrtf((float)(HH*WW)/(Sx[2]*Sy[2]));
        sc4.w = sqrtf((float)(HH*WW)/(Sx[3]*Sy[3]));
    }
    __syncthreads();

    float acc[8][4];
#pragma unroll
    for (int b = 0; b < 8; ++b)
        acc[b][0] = acc[b][1] = acc[b][2] = acc[b][3] = 0.f;

#pragma unroll
    for (int rr = 0; rr < 2; ++rr) {
        const int rrow = r0 + rr;
        const int hh = rrow & (HH - 1);
        float4 gys;
        if constexpr (MODE == 2) {
            float hp = hh * STEP, dd;
            dd=hp-muy4.x; gys.x = __expf(ay4.x*dd*dd) * sc4.x;
            dd=hp-muy4.y; gys.y = __expf(ay4.y*dd*dd) * sc4.y;
            dd=hp-muy4.z; gys.z = __expf(ay4.z*dd*dd) * sc4.z;
            dd=hp-muy4.w; gys.w = __expf(ay4.w*dd*dd) * sc4.w;
        } else {
            gys = ((const float4*)(gyt + (size_t)hh * NN))[tid];
        }
        const float4* wp  = (const float4*)(weights + (size_t)rrow * WW * NN) + tid;
        const float4* gxp = (const float4*)gxt + tid;
        float racc[8][4];
#pragma unroll
        for (int b = 0; b < 8; ++b)
            racc[b][0] = racc[b][1] = racc[b][2] = racc[b][3] = 0.f;
        auto GX = [&](int w) -> float4 {
            if constexpr (MODE == 2) {
                float pp = w * STEP, dd;
                float4 gg;
                dd=pp-mux4.x; gg.x = __expf(ax4.x*dd*dd);
                dd=pp-mux4.y; gg.y = __expf(ax4.y*dd*dd);
                dd=pp-mux4.z; gg.z = __expf(ax4.z*dd*dd);
                dd=pp-mux4.w; gg.w = __expf(ax4.w*dd*dd);
                return gg;
            } else {
                return gxp[(size_t)w * NF4];
            }
        };
#define COMPUTE(WIDX, WT, GXV)                                          \
        {                                                               \
            float4 t;                                                   \
            t.x = GXV.x * WT.x; t.y = GXV.y * WT.y;                     \
            t.z = GXV.z * WT.z; t.w = GXV.w * WT.w;                     \
            const float4* trp = (const float4*)&tile[rr][WIDX][0];      \
            float xs[8];                                                \
            ((float4*)xs)[0] = trp[0]; ((float4*)xs)[1] = trp[1];       \
            _Pragma("unroll")                                           \
            for (int b = 0; b < 8; ++b) {                               \
                racc[b][0] = fmaf(xs[b], t.x, racc[b][0]);              \
                racc[b][1] = fmaf(xs[b], t.y, racc[b][1]);              \
                racc[b][2] = fmaf(xs[b], t.z, racc[b][2]);              \
                racc[b][3] = fmaf(xs[b], t.w, racc[b][3]);              \
            }                                                           \
        }
        float4 wtA = wp[0];
        float4 gxA = GX(0);
        float4 wtB = wp[NF4];
        float4 gxB = GX(1);
        for (int w = 0; w < WW; w += 2) {
            const int wn = (w + 2 < WW) ? (w + 2) : (WW - 2);
            float4 wtA2 = wp[(size_t)wn * NF4];
            float4 gxA2 = GX(wn);
            float4 wtB2 = wp[(size_t)(wn + 1) * NF4];
            float4 gxB2 = GX(wn + 1);
            COMPUTE(w,     wtA, gxA);
            COMPUTE(w + 1, wtB, gxB);
            wtA = wtA2; gxA = gxA2; wtB = wtB2; gxB = gxB2;
        }
#undef COMPUTE
#pragma unroll
        for (int b = 0; b < 8; ++b) {
            acc[b][0] = fmaf(gys.x, racc[b][0], acc[b][0]);
            acc[b][1] = fmaf(gys.y, racc[b][1], acc[b][1]);
            acc[b][2] = fmaf(gys.z, racc[b][2], acc[b][2]);
            acc[b][3] = fmaf(gys.w, racc[b][3], acc[b][3]);
        }
    }

    float* op = dst + (size_t)b0 * NN + tid * 4;
#pragma unroll
    for (int b = 0; b < 8; ++b) {
        atomicAdd(op + (size_t)b * NN + 0, acc[b][0]);
        atomicAdd(op + (size_t)b * NN + 1, acc[b][1]);
        atomicAdd(op + (size_t)b * NN + 2, acc[b][2]);
        atomicAdd(op + (size_t)b * NN + 3, acc[b][3]);
    }
}

extern "C" void kernel_launch(void* const* d_in, const int* in_sizes, int n_in,
                              void* d_out, int out_size, void* d_ws, size_t ws_size,
                              hipStream_t stream) {
    const float* x       = (const float*)d_in[0];
    const float* mu_x    = (const float*)d_in[1];
    const float* mu_y    = (const float*)d_in[2];
    const float* sigma_x = (const float*)d_in[3];
    const float* sigma_y = (const float*)d_in[4];
    const float* weights = (const float*)d_in[5];
    float* out = (float*)d_out;

    float* scale = (float*)d_ws;                          // 4 KB
    float* gxt   = (float*)((char*)d_ws + 4096);          // 512 KB
    float* gyt   = gxt + (size_t)HH * NN;                 // 512 KB
    float* part  = gyt + (size_t)HH * NN;                 // 50.3 MB
    float* part2 = part + (size_t)KSR * BB * NN;          // 1 MB
    const size_t need_tbl  = 4096 + 2 * sizeof(float) * (size_t)HH * NN;
    const size_t need_part = need_tbl +
        sizeof(float) * ((size_t)KSR * BB * NN + (size_t)SG * BB * NN);

    if (ws_size >= need_part) {
        scale_kernel<<<(NN + 255) / 256, 256, 0, stream>>>(mu_x, mu_y, sigma_x, sigma_y, scale);
        table_kernel<<<(HH * NN) / 256, 256, 0, stream>>>(mu_x, mu_y, sigma_x, sigma_y,
                                                          scale, gxt, gyt);
        main_pipe<<<KSR * BSPLIT, 256, 0, stream>>>(weights, x, gyt, mu_x, sigma_x, part);
        reduce1_kernel<<<32 * SG, 256, 0, stream>>>(part, part2);
        reduce2_kernel<<<BB * NN / 4 / 256, 256, 0, stream>>>(part2, out);
    } else if (ws_size >= need_tbl) {
        hipMemsetAsync(d_out, 0, (size_t)out_size * sizeof(float), stream);
        scale_kernel<<<(NN + 255) / 256, 256, 0, stream>>>(mu_x, mu_y, sigma_x, sigma_y, scale);
        table_kernel<<<(HH * NN) / 256, 256, 0, stream>>>(mu_x, mu_y, sigma_x, sigma_y,
                                                          scale, gxt, gyt);
        dim3 grid(NROWS / 2, 4);
        main_fallback<1><<<grid, 256, 0, stream>>>(weights, x, gxt, gyt,
                                                   mu_x, mu_y, sigma_x, sigma_y, out);
    } else {
        hipMemsetAsync(d_out, 0, (size_t)out_size * sizeof(float), stream);
        dim3 grid(NROWS / 2, 4);
        main_fallback<2><<<grid, 256, 0, stream>>>(weights, x, nullptr, nullptr,
                                                   mu_x, mu_y, sigma_x, sigma_y, out);
    }
}

// Round 8
// 74.234 us; speedup vs baseline: 5.9779x; 1.0630x over previous
//
#include <hip/hip_runtime.h>

#define BB 32
#define CC 3
#define HH 128
#define WW 128
#define NN 1024
#define KK (CC*HH*WW)        // 49152
#define NROWS (CC*HH)        // 384
#define KSR NROWS            // 384 split-K groups (1 row each)
#define BH 16                // batches per block
#define BSPLIT (BB/BH)       // 2
#define WCH 4                // w-columns per register chunk
#define NCH (WW/WCH)         // 32 chunks per row
#define SG 8                 // s-groups in reduce stage 1
#define STEP (1.0f/127.0f)

// ---- per-neuron normalization scale: scale[n] = sqrt(H*W/(Sx*Sy)) ----
__global__ void scale_kernel(const float* __restrict__ mu_x,
                             const float* __restrict__ mu_y,
                             const float* __restrict__ sigma_x,
                             const float* __restrict__ sigma_y,
                             float* __restrict__ scale) {
    int n = blockIdx.x * blockDim.x + threadIdx.x;
    if (n >= NN) return;
    float mux = mu_x[n], muy = mu_y[n];
    float isx = 1.0f / sigma_x[n], isy = 1.0f / sigma_y[n];
    float Sx = 0.f, Sy = 0.f;
    for (int i = 0; i < WW; ++i) {
        float dx = (i * STEP - mux) * isx;
        Sx += __expf(-dx * dx);
        float dy = (i * STEP - muy) * isy;
        Sy += __expf(-dy * dy);
    }
    scale[n] = sqrtf((float)(HH * WW) / (Sx * Sy));
}

// ---- transpose x[B,K] -> xT[K,B] (proven R1 kernel) ----
__global__ void xpose_kernel(const float* __restrict__ x, float* __restrict__ xT) {
    __shared__ float tile[64][BB + 1];
    int k0 = blockIdx.x * 64;
    int lane = threadIdx.x & 63;   // k within tile
    int bgrp = threadIdx.x >> 6;   // 0..3
#pragma unroll
    for (int i = 0; i < 8; ++i) {
        int b = bgrp * 8 + i;
        tile[lane][b] = x[(size_t)b * KK + k0 + lane];
    }
    __syncthreads();
    int b = threadIdx.x & 31;
    int kk0 = threadIdx.x >> 5;    // 0..7
#pragma unroll
    for (int i = 0; i < 8; ++i) {
        int kk = i * 8 + kk0;
        xT[(size_t)(k0 + kk) * BB + b] = tile[kk][b];
    }
}

// ---- main v4: zero-LDS register pipeline ----
// block = (row g, batch-half b0); wave owns a 256-n slice; lane owns 4 n.
// Weights double-buffered in VGPRs (compiler-exact counted vmcnt waits);
// x read as wave-uniform float4 from xT (one VMEM request per load).
__global__ __launch_bounds__(256) void main_pipe(
    const float* __restrict__ weights,
    const float* __restrict__ xT,
    const float* __restrict__ scale,
    const float* __restrict__ mu_x, const float* __restrict__ mu_y,
    const float* __restrict__ sigma_x, const float* __restrict__ sigma_y,
    float* __restrict__ part)
{
    const int tid  = threadIdx.x;
    const int wv   = tid >> 6;
    const int lane = tid & 63;

    // XCD swizzle: the 2 batch-half siblings of a row -> same XCD, adjacent.
    const int d    = blockIdx.x;             // 0..767
    const int xcd  = d & 7;
    const int slot = d >> 3;                 // 0..95
    const int g    = xcd * (KSR / 8) + (slot >> 1);   // 0..383
    const int b0   = (slot & 1) * BH;
    const int r    = g;
    const int h    = r & (HH - 1);
    const int nq   = wv * 64 + lane;         // float4 index into n-arrays

    const float4 mux = ((const float4*)mu_x)[nq];
    const float4 sx4 = ((const float4*)sigma_x)[nq];
    const float4 muy = ((const float4*)mu_y)[nq];
    const float4 sy4 = ((const float4*)sigma_y)[nq];
    const float4 sc4 = ((const float4*)scale)[nq];

    float4 ax, axs, Bf, gyrow;
    ax.x = -0.5f/(sx4.x*sx4.x); ax.y = -0.5f/(sx4.y*sx4.y);
    ax.z = -0.5f/(sx4.z*sx4.z); ax.w = -0.5f/(sx4.w*sx4.w);
    axs.x = ax.x*STEP; axs.y = ax.y*STEP; axs.z = ax.z*STEP; axs.w = ax.w*STEP;
    Bf.x = __expf(2.f*axs.x*STEP); Bf.y = __expf(2.f*axs.y*STEP);
    Bf.z = __expf(2.f*axs.z*STEP); Bf.w = __expf(2.f*axs.w*STEP);
    {   // gy[h]*scale inline (no table)
        const float hp = h * STEP;
        float ayc, dd;
        ayc = -0.5f/(sy4.x*sy4.x); dd = hp-muy.x; gyrow.x = __expf(ayc*dd*dd)*sc4.x;
        ayc = -0.5f/(sy4.y*sy4.y); dd = hp-muy.y; gyrow.y = __expf(ayc*dd*dd)*sc4.y;
        ayc = -0.5f/(sy4.z*sy4.z); dd = hp-muy.z; gyrow.z = __expf(ayc*dd*dd)*sc4.z;
        ayc = -0.5f/(sy4.w*sy4.w); dd = hp-muy.w; gyrow.w = __expf(ayc*dd*dd)*sc4.w;
    }

    const float* wbase = weights + (size_t)r * WW * NN + nq * 4;
    const float4* xr4  = (const float4*)xT + (size_t)r * (WW * BB / 4) + (b0 >> 2);
    // per w: xr4[w*8 + q], q = 0..3 (16 batches)

    float4 wR[2][4];                          // double-buffered weight quads
#define WLOAD(BUF, C)                                                   \
    {                                                                   \
        _Pragma("unroll")                                               \
        for (int i = 0; i < 4; ++i)                                     \
            wR[BUF][i] = *(const float4*)(wbase + (size_t)((C)*WCH + i) * NN); \
    }

    float4 acc[BH];
#pragma unroll
    for (int b = 0; b < BH; ++b) acc[b] = make_float4(0.f, 0.f, 0.f, 0.f);

    float4 g4, r4;
    auto resync = [&](int w0) {              // fresh exps, span <= 16 w
        const float w0s = (float)w0 * STEP;
        float dd;
        dd = w0s - mux.x; g4.x = __expf(ax.x*dd*dd)*gyrow.x; r4.x = __expf(axs.x*(2.f*dd+STEP));
        dd = w0s - mux.y; g4.y = __expf(ax.y*dd*dd)*gyrow.y; r4.y = __expf(axs.y*(2.f*dd+STEP));
        dd = w0s - mux.z; g4.z = __expf(ax.z*dd*dd)*gyrow.z; r4.z = __expf(axs.z*(2.f*dd+STEP));
        dd = w0s - mux.w; g4.w = __expf(ax.w*dd*dd)*gyrow.w; r4.w = __expf(axs.w*(2.f*dd+STEP));
    };

#define FMAQ(XQ, A0)                                                    \
    {                                                                   \
        acc[A0+0].x = fmaf(XQ.x, t.x, acc[A0+0].x);                     \
        acc[A0+0].y = fmaf(XQ.x, t.y, acc[A0+0].y);                     \
        acc[A0+0].z = fmaf(XQ.x, t.z, acc[A0+0].z);                     \
        acc[A0+0].w = fmaf(XQ.x, t.w, acc[A0+0].w);                     \
        acc[A0+1].x = fmaf(XQ.y, t.x, acc[A0+1].x);                     \
        acc[A0+1].y = fmaf(XQ.y, t.y, acc[A0+1].y);                     \
        acc[A0+1].z = fmaf(XQ.y, t.z, acc[A0+1].z);                     \
        acc[A0+1].w = fmaf(XQ.y, t.w, acc[A0+1].w);                     \
        acc[A0+2].x = fmaf(XQ.z, t.x, acc[A0+2].x);                     \
        acc[A0+2].y = fmaf(XQ.z, t.y, acc[A0+2].y);                     \
        acc[A0+2].z = fmaf(XQ.z, t.z, acc[A0+2].z);                     \
        acc[A0+2].w = fmaf(XQ.z, t.w, acc[A0+2].w);                     \
        acc[A0+3].x = fmaf(XQ.w, t.x, acc[A0+3].x);                     \
        acc[A0+3].y = fmaf(XQ.w, t.y, acc[A0+3].y);                     \
        acc[A0+3].z = fmaf(XQ.w, t.z, acc[A0+3].z);                     \
        acc[A0+3].w = fmaf(XQ.w, t.w, acc[A0+3].w);                     \
    }

#define CHUNK(BUF, C)                                                   \
    {                                                                   \
        if (((C) & 3) == 0) resync((C) * WCH);                          \
        _Pragma("unroll")                                               \
        for (int i = 0; i < 4; ++i) {                                   \
            const int w = (C) * WCH + i;                                \
            const float4 xq0 = xr4[w*8 + 0];                            \
            const float4 xq1 = xr4[w*8 + 1];                            \
            const float4 xq2 = xr4[w*8 + 2];                            \
            const float4 xq3 = xr4[w*8 + 3];                            \
            const float4 wt  = wR[BUF][i];                              \
            float4 t;                                                   \
            t.x = g4.x * wt.x; t.y = g4.y * wt.y;                       \
            t.z = g4.z * wt.z; t.w = g4.w * wt.w;                       \
            FMAQ(xq0, 0)                                                \
            FMAQ(xq1, 4)                                                \
            FMAQ(xq2, 8)                                                \
            FMAQ(xq3, 12)                                               \
            g4.x *= r4.x; g4.y *= r4.y; g4.z *= r4.z; g4.w *= r4.w;     \
            r4.x *= Bf.x; r4.y *= Bf.y; r4.z *= Bf.z; r4.w *= Bf.w;     \
        }                                                               \
    }

    WLOAD(0, 0);
    for (int c = 0; c < NCH; c += 2) {
        WLOAD(1, c + 1);                     // prefetch next chunk (regs)
        CHUNK(0, c);                         // compute current
        if (c + 2 < NCH) WLOAD(0, c + 2);
        CHUNK(1, c + 1);
    }
#undef CHUNK
#undef FMAQ
#undef WLOAD

    // coalesced float4 stores into this block's private partial slice
    float* pp = part + ((size_t)g * BB + b0) * NN + (tid << 2);
#pragma unroll
    for (int b = 0; b < BH; ++b)
        *(float4*)(pp + (size_t)b * NN) = acc[b];
}

// ---- reduce stage 1: part2[sg][cq] = sum over 48 s of part[s][cq] ----
__global__ __launch_bounds__(256) void reduce1_kernel(const float* __restrict__ part,
                                                      float* __restrict__ part2) {
    const int sg = blockIdx.x >> 5;                       // 0..7
    const int cq = (blockIdx.x & 31) * 256 + threadIdx.x; // cell-quads
    const int s0 = sg * (KSR / SG);
    float4 a = make_float4(0.f, 0.f, 0.f, 0.f);
#pragma unroll 4
    for (int s = 0; s < KSR / SG; ++s) {
        const float4 v = *(const float4*)(part + (size_t)(s0 + s) * (BB * NN) + cq * 4);
        a.x += v.x; a.y += v.y; a.z += v.z; a.w += v.w;
    }
    *(float4*)(part2 + ((size_t)sg * (BB * NN) + cq * 4)) = a;
}

// ---- reduce stage 2: out[cq] = sum over 8 s-groups ----
__global__ __launch_bounds__(256) void reduce2_kernel(const float* __restrict__ part2,
                                                      float* __restrict__ out) {
    const int cq = blockIdx.x * 256 + threadIdx.x;
    float4 a = make_float4(0.f, 0.f, 0.f, 0.f);
#pragma unroll
    for (int sgi = 0; sgi < SG; ++sgi) {
        const float4 v = *(const float4*)(part2 + (size_t)sgi * (BB * NN) + cq * 4);
        a.x += v.x; a.y += v.y; a.z += v.z; a.w += v.w;
    }
    *(float4*)(out + cq * 4) = a;
}

// ---- fallback (atomic, self-contained) — proven R3 structure ----
__global__ __launch_bounds__(256) void main_fallback(
    const float* __restrict__ weights,
    const float* __restrict__ x,
    const float* __restrict__ mu_x, const float* __restrict__ mu_y,
    const float* __restrict__ sigma_x, const float* __restrict__ sigma_y,
    float* __restrict__ dst)
{
    __shared__ float tile[2][WW][8];
    const int tid = threadIdx.x;
    const int g   = blockIdx.x;
    const int b0  = blockIdx.y * 8;
    const int r0  = g * 2;

    {
        const int b = tid & 7;
        const int c = tid >> 3;
        const float* xp = x + (size_t)(b0 + b) * KK + (size_t)r0 * WW + c * 8;
        const float4 v0 = ((const float4*)xp)[0];
        const float4 v1 = ((const float4*)xp)[1];
        const int row = (c * 8) >> 7;
        const int w   = (c * 8) & (WW - 1);
        tile[row][w+0][b] = v0.x; tile[row][w+1][b] = v0.y;
        tile[row][w+2][b] = v0.z; tile[row][w+3][b] = v0.w;
        tile[row][w+4][b] = v1.x; tile[row][w+5][b] = v1.y;
        tile[row][w+6][b] = v1.z; tile[row][w+7][b] = v1.w;
    }

    float4 mux4 = ((const float4*)mu_x)[tid];
    float4 muy4 = ((const float4*)mu_y)[tid];
    float4 sx4  = ((const float4*)sigma_x)[tid];
    float4 sy4  = ((const float4*)sigma_y)[tid];
    float4 ax4, ay4, sc4;
    ax4.x=-0.5f/(sx4.x*sx4.x); ax4.y=-0.5f/(sx4.y*sx4.y);
    ax4.z=-0.5f/(sx4.z*sx4.z); ax4.w=-0.5f/(sx4.w*sx4.w);
    ay4.x=-0.5f/(sy4.x*sy4.x); ay4.y=-0.5f/(sy4.y*sy4.y);
    ay4.z=-0.5f/(sy4.z*sy4.z); ay4.w=-0.5f/(sy4.w*sy4.w);
    {
        float Sx[4]={0,0,0,0}, Sy[4]={0,0,0,0};
        for (int i = 0; i < WW; ++i) {
            float pp = i * STEP, dd;
            dd=pp-mux4.x; Sx[0]+=__expf(2.f*ax4.x*dd*dd);
            dd=pp-mux4.y; Sx[1]+=__expf(2.f*ax4.y*dd*dd);
            dd=pp-mux4.z; Sx[2]+=__expf(2.f*ax4.z*dd*dd);
            dd=pp-mux4.w; Sx[3]+=__expf(2.f*ax4.w*dd*dd);
            dd=pp-muy4.x; Sy[0]+=__expf(2.f*ay4.x*dd*dd);
            dd=pp-muy4.y; Sy[1]+=__expf(2.f*ay4.y*dd*dd);
            dd=pp-muy4.z; Sy[2]+=__expf(2.f*ay4.z*dd*dd);
            dd=pp-muy4.w; Sy[3]+=__expf(2.f*ay4.w*dd*dd);
        }
        sc4.x = sqrtf((float)(HH*WW)/(Sx[0]*Sy[0]));
        sc4.y = sqrtf((float)(HH*WW)/(Sx[1]*Sy[1]));
        sc4.z = sqrtf((float)(HH*WW)/(Sx[2]*Sy[2]));
        sc4.w = sqrtf((float)(HH*WW)/(Sx[3]*Sy[3]));
    }
    __syncthreads();

    float acc[8][4];
#pragma unroll
    for (int b = 0; b < 8; ++b)
        acc[b][0] = acc[b][1] = acc[b][2] = acc[b][3] = 0.f;

#pragma unroll
    for (int rr = 0; rr < 2; ++rr) {
        const int rrow = r0 + rr;
        const int hh = rrow & (HH - 1);
        float4 gys;
        {
            float hp = hh * STEP, dd;
            dd=hp-muy4.x; gys.x = __expf(ay4.x*dd*dd) * sc4.x;
            dd=hp-muy4.y; gys.y = __expf(ay4.y*dd*dd) * sc4.y;
            dd=hp-muy4.z; gys.z = __expf(ay4.z*dd*dd) * sc4.z;
            dd=hp-muy4.w; gys.w = __expf(ay4.w*dd*dd) * sc4.w;
        }
        const float4* wp = (const float4*)(weights + (size_t)rrow * WW * NN) + tid;
        float racc[8][4];
#pragma unroll
        for (int b = 0; b < 8; ++b)
            racc[b][0] = racc[b][1] = racc[b][2] = racc[b][3] = 0.f;
        for (int w = 0; w < WW; ++w) {
            const float4 wt = wp[(size_t)w * (NN/4)];
            float pp = w * STEP, dd;
            float4 t;
            dd=pp-mux4.x; t.x = __expf(ax4.x*dd*dd) * wt.x;
            dd=pp-mux4.y; t.y = __expf(ax4.y*dd*dd) * wt.y;
            dd=pp-mux4.z; t.z = __expf(ax4.z*dd*dd) * wt.z;
            dd=pp-mux4.w; t.w = __expf(ax4.w*dd*dd) * wt.w;
            const float4* trp = (const float4*)&tile[rr][w][0];
            float xs[8];
            ((float4*)xs)[0] = trp[0]; ((float4*)xs)[1] = trp[1];
#pragma unroll
            for (int b = 0; b < 8; ++b) {
                racc[b][0] = fmaf(xs[b], t.x, racc[b][0]);
                racc[b][1] = fmaf(xs[b], t.y, racc[b][1]);
                racc[b][2] = fmaf(xs[b], t.z, racc[b][2]);
                racc[b][3] = fmaf(xs[b], t.w, racc[b][3]);
            }
        }
#pragma unroll
        for (int b = 0; b < 8; ++b) {
            acc[b][0] = fmaf(gys.x, racc[b][0], acc[b][0]);
            acc[b][1] = fmaf(gys.y, racc[b][1], acc[b][1]);
            acc[b][2] = fmaf(gys.z, racc[b][2], acc[b][2]);
            acc[b][3] = fmaf(gys.w, racc[b][3], acc[b][3]);
        }
    }

    float* op = dst + (size_t)b0 * NN + tid * 4;
#pragma unroll
    for (int b = 0; b < 8; ++b) {
        atomicAdd(op + (size_t)b * NN + 0, acc[b][0]);
        atomicAdd(op + (size_t)b * NN + 1, acc[b][1]);
        atomicAdd(op + (size_t)b * NN + 2, acc[b][2]);
        atomicAdd(op + (size_t)b * NN + 3, acc[b][3]);
    }
}

extern "C" void kernel_launch(void* const* d_in, const int* in_sizes, int n_in,
                              void* d_out, int out_size, void* d_ws, size_t ws_size,
                              hipStream_t stream) {
    const float* x       = (const float*)d_in[0];
    const float* mu_x    = (const float*)d_in[1];
    const float* mu_y    = (const float*)d_in[2];
    const float* sigma_x = (const float*)d_in[3];
    const float* sigma_y = (const float*)d_in[4];
    const float* weights = (const float*)d_in[5];
    float* out = (float*)d_out;

    float* scale = (float*)d_ws;                          // 4 KB
    float* xT    = (float*)((char*)d_ws + 4096);          // 6.3 MB
    float* part  = xT + (size_t)KK * BB;                  // 50.3 MB
    float* part2 = part + (size_t)KSR * BB * NN;          // 1 MB
    const size_t need = 4096 +
        sizeof(float) * ((size_t)KK * BB + (size_t)KSR * BB * NN + (size_t)SG * BB * NN);

    if (ws_size >= need) {
        scale_kernel<<<(NN + 255) / 256, 256, 0, stream>>>(mu_x, mu_y, sigma_x, sigma_y, scale);
        xpose_kernel<<<KK / 64, 256, 0, stream>>>(x, xT);
        main_pipe<<<KSR * BSPLIT, 256, 0, stream>>>(weights, xT, scale,
                                                    mu_x, mu_y, sigma_x, sigma_y, part);
        reduce1_kernel<<<32 * SG, 256, 0, stream>>>(part, part2);
        reduce2_kernel<<<BB * NN / 4 / 256, 256, 0, stream>>>(part2, out);
    } else {
        hipMemsetAsync(d_out, 0, (size_t)out_size * sizeof(float), stream);
        dim3 grid(NROWS / 2, 4);
        main_fallback<<<grid, 256, 0, stream>>>(weights, x,
                                                mu_x, mu_y, sigma_x, sigma_y, out);
    }
}